// Round 1
// baseline (6433.326 us; speedup 1.0000x reference)
//
#include <hip/hip_runtime.h>

#define NGRAPH 512
#define NNODE  128
#define NEDGE  512
#define EMB    300
#define NLAYER 5
#define FA     9
#define FB     3
#define VV     64

// ---------------------------------------------------------------------------
// Kernel 1: atom encode + edge weights + dense normalized-adjacency diffusion
// One block per graph. LDS: A[128][129] + 2 x-chunks [128][68] + edge staging.
// ---------------------------------------------------------------------------
__global__ __launch_bounds__(256)
void diffuse_kernel(const int* __restrict__ order_p,
                    const int* __restrict__ x_atom,
                    const int* __restrict__ edge_index,
                    const int* __restrict__ edge_attr,
                    const float* __restrict__ atom_tab,
                    const float* __restrict__ bond_tab_root,
                    const float* __restrict__ edge_lin_w,
                    const float* __restrict__ edge_lin_b,
                    float* __restrict__ h)
{
    __shared__ float A[128 * 129];       // 66,048 B  (adj then normalized A)
    __shared__ float xb[2 * 128 * 68];   // 69,632 B  (prio ints first, then x ping-pong)
    __shared__ float ew_s[NEDGE];        // 2,048 B
    __shared__ int   es[NEDGE];          // 2,048 B   (r | c<<8)
    __shared__ int   xat[128 * FA];      // 4,608 B
    __shared__ float rinv[128];
    __shared__ float cinv[128];

    const int tid = threadIdx.x;
    const int g   = blockIdx.x;

    // ---- stage edges + atom indices, zero A and priorities ----
    for (int e = tid; e < NEDGE; e += 256) {
        int r = edge_index[(g * 2 + 0) * NEDGE + e];
        int c = edge_index[(g * 2 + 1) * NEDGE + e];
        es[e] = r | (c << 8);
    }
    for (int i = tid; i < 128 * FA; i += 256) xat[i] = x_atom[g * 128 * FA + i];
    int* prio = (int*)xb;
    for (int i = tid; i < 128 * 129; i += 256) A[i] = 0.f;
    for (int i = tid; i < 128 * 128; i += 256) prio[i] = -1;
    __syncthreads();

    // ---- edge weights: ew = sigmoid(e_emb . w + b), one wave per 128 edges ----
    {
        const int wave = tid >> 6, lane = tid & 63;
        const float elb = edge_lin_b[0];
        for (int e = wave * 128; e < wave * 128 + 128; ++e) {
            const int base = (g * NEDGE + e) * 3;
            const int a0 = edge_attr[base + 0];
            const int a1 = edge_attr[base + 1];
            const int a2 = edge_attr[base + 2];
            const float* t0 = bond_tab_root + (0 * VV + a0) * EMB;
            const float* t1 = bond_tab_root + (1 * VV + a1) * EMB;
            const float* t2 = bond_tab_root + (2 * VV + a2) * EMB;
            float acc = 0.f;
            for (int d = lane; d < EMB; d += 64)
                acc += (t0[d] + t1[d] + t2[d]) * edge_lin_w[d];
            #pragma unroll
            for (int off = 32; off > 0; off >>= 1) acc += __shfl_xor(acc, off, 64);
            if (lane == 0) ew_s[e] = 1.f / (1.f + expf(-(acc + elb)));
        }
    }
    __syncthreads();

    // ---- adjacency scatter with numpy sequential last-wins semantics ----
    // priority: phase-1 (r,c) = e, phase-2 (c,r) = 512+e; max priority wins.
    for (int e = tid; e < NEDGE; e += 256) {
        int r = es[e] & 255, c = es[e] >> 8;
        atomicMax(&prio[r * 128 + c], e);
        atomicMax(&prio[c * 128 + r], 512 + e);
    }
    __syncthreads();
    for (int e = tid; e < NEDGE; e += 256) {
        int r = es[e] & 255, c = es[e] >> 8;
        if (prio[r * 128 + c] == e)       A[r * 129 + c] = ew_s[e];
        if (prio[c * 128 + r] == 512 + e) A[c * 129 + r] = ew_s[e];
    }
    __syncthreads();
    if (tid < 128) A[tid * 129 + tid] += 1.f;   // + I
    __syncthreads();
    if (tid < 128) {
        float rs = 0.f, cs = 0.f;
        for (int j = 0; j < 128; ++j) { rs += A[tid * 129 + j]; cs += A[j * 129 + tid]; }
        rinv[tid] = 1.f / sqrtf(rs);   // rowsum(j)^-0.5  (applied on column j)
        cinv[tid] = 1.f / sqrtf(cs);   // colsum(i)^-0.5  (applied on row i)
    }
    __syncthreads();
    for (int i = tid; i < 128 * 128; i += 256) {
        int r = i >> 7, c = i & 127;
        A[r * 129 + c] *= cinv[r] * rinv[c];
    }

    // ---- diffusion: y = (fea + A fea + A^2 fea + ... ) / (ord+1), dim-chunked ----
    const int   ord    = order_p[0];
    const float yscale = 1.f / (float)(ord + 1);
    const int rg = tid >> 3, dg = tid & 7;
    const int i0 = rg * 4, d0 = dg * 8;     // 4 rows x 8 dims per thread
    float* x0 = xb;
    float* x1 = xb + 128 * 68;

    for (int cb = 0; cb < 5; ++cb) {
        const int dbase = cb * 64;
        __syncthreads();   // A ready / previous chunk fully consumed

        // encode fea chunk (x_atom table-lookup sum, * (1-DROP)=0.8)
        float y[4][8];
        #pragma unroll
        for (int ii = 0; ii < 4; ++ii)
            #pragma unroll
            for (int dd = 0; dd < 8; ++dd) y[ii][dd] = 0.f;
        #pragma unroll
        for (int f = 0; f < FA; ++f) {
            #pragma unroll
            for (int ii = 0; ii < 4; ++ii) {
                const int idx = xat[(i0 + ii) * FA + f];
                const float* row = atom_tab + (size_t)(f * VV + idx) * EMB + dbase + d0;
                #pragma unroll
                for (int dd = 0; dd < 8; ++dd)
                    if (dbase + d0 + dd < EMB) y[ii][dd] += row[dd];
            }
        }
        #pragma unroll
        for (int ii = 0; ii < 4; ++ii)
            #pragma unroll
            for (int dd = 0; dd < 8; ++dd) {
                y[ii][dd] *= 0.8f;
                x0[(i0 + ii) * 68 + d0 + dd] = y[ii][dd];  // 0 where d>=EMB
            }
        float* cur = x0;
        float* nxt = x1;
        __syncthreads();

        for (int o = 0; o < ord; ++o) {
            float r[4][8];
            #pragma unroll
            for (int ii = 0; ii < 4; ++ii)
                #pragma unroll
                for (int dd = 0; dd < 8; ++dd) r[ii][dd] = 0.f;
            for (int j = 0; j < 128; ++j) {
                const float a0 = A[(i0 + 0) * 129 + j];
                const float a1 = A[(i0 + 1) * 129 + j];
                const float a2 = A[(i0 + 2) * 129 + j];
                const float a3 = A[(i0 + 3) * 129 + j];
                const float* xr = &cur[j * 68 + d0];
                const float4 xv0 = *(const float4*)&xr[0];
                const float4 xv1 = *(const float4*)&xr[4];
                const float xv[8] = {xv0.x, xv0.y, xv0.z, xv0.w,
                                     xv1.x, xv1.y, xv1.z, xv1.w};
                #pragma unroll
                for (int dd = 0; dd < 8; ++dd) {
                    r[0][dd] += a0 * xv[dd];
                    r[1][dd] += a1 * xv[dd];
                    r[2][dd] += a2 * xv[dd];
                    r[3][dd] += a3 * xv[dd];
                }
            }
            #pragma unroll
            for (int ii = 0; ii < 4; ++ii)
                #pragma unroll
                for (int dd = 0; dd < 8; ++dd) {
                    nxt[(i0 + ii) * 68 + d0 + dd] = r[ii][dd];
                    y[ii][dd] += r[ii][dd];
                }
            __syncthreads();
            float* t = cur; cur = nxt; nxt = t;
        }

        #pragma unroll
        for (int ii = 0; ii < 4; ++ii) {
            float* hrow = h + (size_t)(g * 128 + i0 + ii) * EMB + dbase + d0;
            #pragma unroll
            for (int dd = 0; dd < 8; ++dd)
                if (dbase + d0 + dd < EMB) hrow[dd] = y[ii][dd] * yscale;
        }
    }
}

// ---------------------------------------------------------------------------
// Kernel 2: GIN aggregation, in-place:  h <- (1+eps)h + segsum(relu(h[src]+ee))
// One block per graph; dims processed in two halves of 150 so h-slice + agg
// both fit in LDS. Waves partition dst nodes by (dst & 3) -> no atomics,
// deterministic edge order.
// ---------------------------------------------------------------------------
__global__ __launch_bounds__(256)
void agg_kernel(const int* __restrict__ edge_index,
                const int* __restrict__ edge_attr,
                const float* __restrict__ bond_tabs,
                const float* __restrict__ eps_all,
                const int l,
                float* __restrict__ h)
{
    __shared__ float hs[128 * 150];   // 76,800 B
    __shared__ float ag[128 * 150];   // 76,800 B
    __shared__ int   es[NEDGE];       // src | dst<<8
    __shared__ int   eas[NEDGE];      // a0 | a1<<6 | a2<<12

    const int tid = threadIdx.x;
    const int g   = blockIdx.x;
    const float epl = 1.f + eps_all[l];
    const float* bt = bond_tabs + (size_t)l * FB * VV * EMB;

    for (int e = tid; e < NEDGE; e += 256) {
        int s_ = edge_index[(g * 2 + 0) * NEDGE + e];
        int d_ = edge_index[(g * 2 + 1) * NEDGE + e];
        es[e] = s_ | (d_ << 8);
        const int base = (g * NEDGE + e) * 3;
        eas[e] = edge_attr[base + 0] | (edge_attr[base + 1] << 6) | (edge_attr[base + 2] << 12);
    }

    const int wave = tid >> 6, lane = tid & 63;

    for (int half = 0; half < 2; ++half) {
        const int doff = half * 150;
        __syncthreads();
        for (int idx = tid; idx < 128 * 150; idx += 256) {
            const int i = idx / 150, d = idx - i * 150;
            const float v = h[(size_t)(g * 128 + i) * EMB + doff + d];
            hs[idx] = v;
            ag[idx] = epl * v;
        }
        __syncthreads();
        for (int e = 0; e < NEDGE; ++e) {
            const int dnode = es[e] >> 8;
            if ((dnode & 3) != wave) continue;     // wave owns dst%4==wave
            const int snode = es[e] & 255;
            const int pk = eas[e];
            const float* t0 = bt + ((pk) & 63) * EMB + doff;
            const float* t1 = bt + (64 + ((pk >> 6) & 63)) * EMB + doff;
            const float* t2 = bt + (128 + ((pk >> 12) & 63)) * EMB + doff;
            for (int d = lane; d < 150; d += 64) {
                float m = hs[snode * 150 + d] + t0[d] + t1[d] + t2[d];
                m = fmaxf(m, 0.f);
                ag[dnode * 150 + d] += m;
            }
        }
        __syncthreads();
        for (int idx = tid; idx < 128 * 150; idx += 256) {
            const int i = idx / 150, d = idx - i * 150;
            h[(size_t)(g * 128 + i) * EMB + doff + d] = ag[idx];
        }
    }
}

// ---------------------------------------------------------------------------
// Kernel 3: fp32 GEMM  C[M,N] = A[M,K] @ B[K,N],
// epilogue: C = gam*(C + bias) + bet, optional relu.
// BM=128, BN=64, BK=16, 256 threads, 8x4 per-thread tile.
// ---------------------------------------------------------------------------
template <int RELU>
__global__ __launch_bounds__(256)
void gemm_ep(const float* __restrict__ A, const float* __restrict__ B,
             float* __restrict__ C, const int M, const int N, const int K,
             const float* __restrict__ bias, const float* __restrict__ gam,
             const float* __restrict__ bet)
{
    __shared__ float As[16][132];   // transposed: As[k][m]
    __shared__ float Bs[16][68];

    const int tid = threadIdx.x;
    const int bn  = blockIdx.x * 64;
    const int bm  = blockIdx.y * 128;
    const int ty  = tid >> 4, tx = tid & 15;
    const int m0  = ty * 8, n0 = tx * 4;

    float acc[8][4];
    #pragma unroll
    for (int i = 0; i < 8; ++i)
        #pragma unroll
        for (int j = 0; j < 4; ++j) acc[i][j] = 0.f;

    const int nT = (K + 15) / 16;
    for (int t = 0; t < nT; ++t) {
        const int k0 = t * 16;
        // A tile: 128 rows x 16 k, loaded as float4, stored transposed
        for (int v = tid; v < 512; v += 256) {
            const int row = v >> 2, c4 = (v & 3) * 4;
            const int gk = k0 + c4;
            float4 val;
            if (gk + 3 < K) {
                val = *(const float4*)&A[(size_t)(bm + row) * K + gk];
            } else {
                float tmp[4];
                #pragma unroll
                for (int q = 0; q < 4; ++q)
                    tmp[q] = (gk + q < K) ? A[(size_t)(bm + row) * K + gk + q] : 0.f;
                val = make_float4(tmp[0], tmp[1], tmp[2], tmp[3]);
            }
            As[c4 + 0][row] = val.x;
            As[c4 + 1][row] = val.y;
            As[c4 + 2][row] = val.z;
            As[c4 + 3][row] = val.w;
        }
        // B tile: 16 k-rows x 64 n
        {
            const int row = tid >> 4, c4 = (tid & 15) * 4;
            const int gk = k0 + row;
            float4 val = make_float4(0.f, 0.f, 0.f, 0.f);
            if (gk < K) {
                const int gn = bn + c4;
                if (gn + 3 < N) {
                    val = *(const float4*)&B[(size_t)gk * N + gn];
                } else {
                    float tmp[4];
                    #pragma unroll
                    for (int q = 0; q < 4; ++q)
                        tmp[q] = (gn + q < N) ? B[(size_t)gk * N + gn + q] : 0.f;
                    val = make_float4(tmp[0], tmp[1], tmp[2], tmp[3]);
                }
            }
            *(float4*)&Bs[row][c4] = val;
        }
        __syncthreads();
        #pragma unroll
        for (int kk = 0; kk < 16; ++kk) {
            const float4 a0 = *(const float4*)&As[kk][m0];
            const float4 a1 = *(const float4*)&As[kk][m0 + 4];
            const float4 b  = *(const float4*)&Bs[kk][n0];
            const float am[8] = {a0.x, a0.y, a0.z, a0.w, a1.x, a1.y, a1.z, a1.w};
            const float bv[4] = {b.x, b.y, b.z, b.w};
            #pragma unroll
            for (int i = 0; i < 8; ++i)
                #pragma unroll
                for (int j = 0; j < 4; ++j) acc[i][j] += am[i] * bv[j];
        }
        __syncthreads();
    }

    float g4[4] = {0, 0, 0, 0}, b4[4] = {0, 0, 0, 0}, e4[4] = {0, 0, 0, 0};
    #pragma unroll
    for (int j = 0; j < 4; ++j) {
        const int n = bn + n0 + j;
        if (n < N) { g4[j] = gam[n]; b4[j] = bias[n]; e4[j] = bet[n]; }
    }
    #pragma unroll
    for (int i = 0; i < 8; ++i) {
        const size_t m = bm + m0 + i;
        #pragma unroll
        for (int j = 0; j < 4; ++j) {
            const int n = bn + n0 + j;
            if (n < N) {
                float v = g4[j] * (acc[i][j] + b4[j]) + e4[j];
                if (RELU) v = fmaxf(v, 0.f);
                C[m * N + n] = v;
            }
        }
    }
}

// ---------------------------------------------------------------------------
extern "C" void kernel_launch(void* const* d_in, const int* in_sizes, int n_in,
                              void* d_out, int out_size, void* d_ws, size_t ws_size,
                              hipStream_t stream)
{
    const int*   order_p       = (const int*)d_in[0];
    const int*   x_atom        = (const int*)d_in[1];
    const int*   edge_index    = (const int*)d_in[2];
    const int*   edge_attr     = (const int*)d_in[3];
    const float* atom_tab      = (const float*)d_in[4];
    const float* bond_tab_root = (const float*)d_in[5];
    const float* edge_lin_w    = (const float*)d_in[6];
    const float* edge_lin_b    = (const float*)d_in[7];
    const float* bond_tabs     = (const float*)d_in[8];
    const float* eps           = (const float*)d_in[9];
    const float* w1            = (const float*)d_in[10];
    const float* b1            = (const float*)d_in[11];
    const float* bn1g          = (const float*)d_in[12];
    const float* bn1b          = (const float*)d_in[13];
    const float* w2            = (const float*)d_in[14];
    const float* b2            = (const float*)d_in[15];
    const float* bng           = (const float*)d_in[16];
    const float* bnb           = (const float*)d_in[17];

    float* h  = (float*)d_out;  // h lives in d_out: [65536][300], rewritten fully each call
    float* z1 = (float*)d_ws;   // [65536][600] fp32 = 157.3 MB

    diffuse_kernel<<<NGRAPH, 256, 0, stream>>>(order_p, x_atom, edge_index, edge_attr,
                                               atom_tab, bond_tab_root, edge_lin_w,
                                               edge_lin_b, h);

    for (int l = 0; l < NLAYER; ++l) {
        agg_kernel<<<NGRAPH, 256, 0, stream>>>(edge_index, edge_attr, bond_tabs, eps, l, h);
        gemm_ep<1><<<dim3(10, 512), 256, 0, stream>>>(h, w1 + (size_t)l * EMB * 2 * EMB, z1,
                                                      65536, 600, 300,
                                                      b1 + l * 600, bn1g + l * 600, bn1b + l * 600);
        if (l < NLAYER - 1) {
            gemm_ep<1><<<dim3(5, 512), 256, 0, stream>>>(z1, w2 + (size_t)l * 2 * EMB * EMB, h,
                                                         65536, 300, 600,
                                                         b2 + l * 300, bng + l * 300, bnb + l * 300);
        } else {
            gemm_ep<0><<<dim3(5, 512), 256, 0, stream>>>(z1, w2 + (size_t)l * 2 * EMB * EMB, h,
                                                         65536, 300, 600,
                                                         b2 + l * 300, bng + l * 300, bnb + l * 300);
        }
    }
}

// Round 2
// 4332.173 us; speedup vs baseline: 1.4850x; 1.4850x over previous
//
#include <hip/hip_runtime.h>

#define NGRAPH 512
#define NNODE  128
#define NEDGE  512
#define EMB    300
#define NLAYER 5
#define FA     9
#define FB     3
#define VV     64

typedef __bf16 bf16x8 __attribute__((ext_vector_type(8)));
typedef float  f32x4  __attribute__((ext_vector_type(4)));

__device__ __forceinline__ void gload_lds16(const void* gptr, void* lptr) {
    __builtin_amdgcn_global_load_lds(
        (const __attribute__((address_space(1))) void*)gptr,
        (__attribute__((address_space(3))) void*)lptr, 16, 0, 0);
}

// ---------------------------------------------------------------------------
// Kernel 0: weight prep — transpose w1/w2 to bf16 [N][K], K padded to x32,
// N padded to the 64-wide GEMM block grid (pad rows/cols zeroed).
// w1t: [L][640][320]  (real 600 x 300);  w2t: [L][320][640] (real 300 x 600)
// ---------------------------------------------------------------------------
__global__ __launch_bounds__(256)
void prep_w_kernel(const float* __restrict__ w1, const float* __restrict__ w2,
                   __bf16* __restrict__ w1t, __bf16* __restrict__ w2t)
{
    const int i = blockIdx.x * 256 + threadIdx.x;
    const int T1 = NLAYER * 640 * 320;
    const int T2 = NLAYER * 320 * 640;
    if (i < T1) {
        const int l = i / (640 * 320);
        const int r = i - l * 640 * 320;
        const int n = r / 320, k = r - n * 320;
        float v = (n < 600 && k < 300) ? w1[((size_t)l * 300 + k) * 600 + n] : 0.f;
        w1t[i] = (__bf16)v;
    } else if (i < T1 + T2) {
        const int j = i - T1;
        const int l = j / (320 * 640);
        const int r = j - l * 320 * 640;
        const int n = r / 640, k = r - n * 640;
        float v = (n < 300 && k < 600) ? w2[((size_t)l * 600 + k) * 300 + n] : 0.f;
        w2t[j] = (__bf16)v;
    }
}

// ---------------------------------------------------------------------------
// Kernel 1: atom encode + edge weights + dense normalized-adjacency diffusion
// (unchanged from round 0)
// ---------------------------------------------------------------------------
__global__ __launch_bounds__(256)
void diffuse_kernel(const int* __restrict__ order_p,
                    const int* __restrict__ x_atom,
                    const int* __restrict__ edge_index,
                    const int* __restrict__ edge_attr,
                    const float* __restrict__ atom_tab,
                    const float* __restrict__ bond_tab_root,
                    const float* __restrict__ edge_lin_w,
                    const float* __restrict__ edge_lin_b,
                    float* __restrict__ h)
{
    __shared__ float A[128 * 129];
    __shared__ float xb[2 * 128 * 68];
    __shared__ float ew_s[NEDGE];
    __shared__ int   es[NEDGE];
    __shared__ int   xat[128 * FA];
    __shared__ float rinv[128];
    __shared__ float cinv[128];

    const int tid = threadIdx.x;
    const int g   = blockIdx.x;

    for (int e = tid; e < NEDGE; e += 256) {
        int r = edge_index[(g * 2 + 0) * NEDGE + e];
        int c = edge_index[(g * 2 + 1) * NEDGE + e];
        es[e] = r | (c << 8);
    }
    for (int i = tid; i < 128 * FA; i += 256) xat[i] = x_atom[g * 128 * FA + i];
    int* prio = (int*)xb;
    for (int i = tid; i < 128 * 129; i += 256) A[i] = 0.f;
    for (int i = tid; i < 128 * 128; i += 256) prio[i] = -1;
    __syncthreads();

    {
        const int wave = tid >> 6, lane = tid & 63;
        const float elb = edge_lin_b[0];
        for (int e = wave * 128; e < wave * 128 + 128; ++e) {
            const int base = (g * NEDGE + e) * 3;
            const int a0 = edge_attr[base + 0];
            const int a1 = edge_attr[base + 1];
            const int a2 = edge_attr[base + 2];
            const float* t0 = bond_tab_root + (0 * VV + a0) * EMB;
            const float* t1 = bond_tab_root + (1 * VV + a1) * EMB;
            const float* t2 = bond_tab_root + (2 * VV + a2) * EMB;
            float acc = 0.f;
            for (int d = lane; d < EMB; d += 64)
                acc += (t0[d] + t1[d] + t2[d]) * edge_lin_w[d];
            #pragma unroll
            for (int off = 32; off > 0; off >>= 1) acc += __shfl_xor(acc, off, 64);
            if (lane == 0) ew_s[e] = 1.f / (1.f + expf(-(acc + elb)));
        }
    }
    __syncthreads();

    for (int e = tid; e < NEDGE; e += 256) {
        int r = es[e] & 255, c = es[e] >> 8;
        atomicMax(&prio[r * 128 + c], e);
        atomicMax(&prio[c * 128 + r], 512 + e);
    }
    __syncthreads();
    for (int e = tid; e < NEDGE; e += 256) {
        int r = es[e] & 255, c = es[e] >> 8;
        if (prio[r * 128 + c] == e)       A[r * 129 + c] = ew_s[e];
        if (prio[c * 128 + r] == 512 + e) A[c * 129 + r] = ew_s[e];
    }
    __syncthreads();
    if (tid < 128) A[tid * 129 + tid] += 1.f;
    __syncthreads();
    if (tid < 128) {
        float rs = 0.f, cs = 0.f;
        for (int j = 0; j < 128; ++j) { rs += A[tid * 129 + j]; cs += A[j * 129 + tid]; }
        rinv[tid] = 1.f / sqrtf(rs);
        cinv[tid] = 1.f / sqrtf(cs);
    }
    __syncthreads();
    for (int i = tid; i < 128 * 128; i += 256) {
        int r = i >> 7, c = i & 127;
        A[r * 129 + c] *= cinv[r] * rinv[c];
    }

    const int   ord    = order_p[0];
    const float yscale = 1.f / (float)(ord + 1);
    const int rg = tid >> 3, dg = tid & 7;
    const int i0 = rg * 4, d0 = dg * 8;
    float* x0 = xb;
    float* x1 = xb + 128 * 68;

    for (int cb = 0; cb < 5; ++cb) {
        const int dbase = cb * 64;
        __syncthreads();

        float y[4][8];
        #pragma unroll
        for (int ii = 0; ii < 4; ++ii)
            #pragma unroll
            for (int dd = 0; dd < 8; ++dd) y[ii][dd] = 0.f;
        #pragma unroll
        for (int f = 0; f < FA; ++f) {
            #pragma unroll
            for (int ii = 0; ii < 4; ++ii) {
                const int idx = xat[(i0 + ii) * FA + f];
                const float* row = atom_tab + (size_t)(f * VV + idx) * EMB + dbase + d0;
                #pragma unroll
                for (int dd = 0; dd < 8; ++dd)
                    if (dbase + d0 + dd < EMB) y[ii][dd] += row[dd];
            }
        }
        #pragma unroll
        for (int ii = 0; ii < 4; ++ii)
            #pragma unroll
            for (int dd = 0; dd < 8; ++dd) {
                y[ii][dd] *= 0.8f;
                x0[(i0 + ii) * 68 + d0 + dd] = y[ii][dd];
            }
        float* cur = x0;
        float* nxt = x1;
        __syncthreads();

        for (int o = 0; o < ord; ++o) {
            float r[4][8];
            #pragma unroll
            for (int ii = 0; ii < 4; ++ii)
                #pragma unroll
                for (int dd = 0; dd < 8; ++dd) r[ii][dd] = 0.f;
            for (int j = 0; j < 128; ++j) {
                const float a0 = A[(i0 + 0) * 129 + j];
                const float a1 = A[(i0 + 1) * 129 + j];
                const float a2 = A[(i0 + 2) * 129 + j];
                const float a3 = A[(i0 + 3) * 129 + j];
                const float* xr = &cur[j * 68 + d0];
                const float4 xv0 = *(const float4*)&xr[0];
                const float4 xv1 = *(const float4*)&xr[4];
                const float xv[8] = {xv0.x, xv0.y, xv0.z, xv0.w,
                                     xv1.x, xv1.y, xv1.z, xv1.w};
                #pragma unroll
                for (int dd = 0; dd < 8; ++dd) {
                    r[0][dd] += a0 * xv[dd];
                    r[1][dd] += a1 * xv[dd];
                    r[2][dd] += a2 * xv[dd];
                    r[3][dd] += a3 * xv[dd];
                }
            }
            #pragma unroll
            for (int ii = 0; ii < 4; ++ii)
                #pragma unroll
                for (int dd = 0; dd < 8; ++dd) {
                    nxt[(i0 + ii) * 68 + d0 + dd] = r[ii][dd];
                    y[ii][dd] += r[ii][dd];
                }
            __syncthreads();
            float* t = cur; cur = nxt; nxt = t;
        }

        #pragma unroll
        for (int ii = 0; ii < 4; ++ii) {
            float* hrow = h + (size_t)(g * 128 + i0 + ii) * EMB + dbase + d0;
            #pragma unroll
            for (int dd = 0; dd < 8; ++dd)
                if (dbase + d0 + dd < EMB) hrow[dd] = y[ii][dd] * yscale;
        }
    }
}

// ---------------------------------------------------------------------------
// Kernel 2: GIN aggregation (unchanged from round 0)
// ---------------------------------------------------------------------------
__global__ __launch_bounds__(256)
void agg_kernel(const int* __restrict__ edge_index,
                const int* __restrict__ edge_attr,
                const float* __restrict__ bond_tabs,
                const float* __restrict__ eps_all,
                const int l,
                float* __restrict__ h)
{
    __shared__ float hs[128 * 150];
    __shared__ float ag[128 * 150];
    __shared__ int   es[NEDGE];
    __shared__ int   eas[NEDGE];

    const int tid = threadIdx.x;
    const int g   = blockIdx.x;
    const float epl = 1.f + eps_all[l];
    const float* bt = bond_tabs + (size_t)l * FB * VV * EMB;

    for (int e = tid; e < NEDGE; e += 256) {
        int s_ = edge_index[(g * 2 + 0) * NEDGE + e];
        int d_ = edge_index[(g * 2 + 1) * NEDGE + e];
        es[e] = s_ | (d_ << 8);
        const int base = (g * NEDGE + e) * 3;
        eas[e] = edge_attr[base + 0] | (edge_attr[base + 1] << 6) | (edge_attr[base + 2] << 12);
    }

    const int wave = tid >> 6, lane = tid & 63;

    for (int half = 0; half < 2; ++half) {
        const int doff = half * 150;
        __syncthreads();
        for (int idx = tid; idx < 128 * 150; idx += 256) {
            const int i = idx / 150, d = idx - i * 150;
            const float v = h[(size_t)(g * 128 + i) * EMB + doff + d];
            hs[idx] = v;
            ag[idx] = epl * v;
        }
        __syncthreads();
        for (int e = 0; e < NEDGE; ++e) {
            const int dnode = es[e] >> 8;
            if ((dnode & 3) != wave) continue;
            const int snode = es[e] & 255;
            const int pk = eas[e];
            const float* t0 = bt + ((pk) & 63) * EMB + doff;
            const float* t1 = bt + (64 + ((pk >> 6) & 63)) * EMB + doff;
            const float* t2 = bt + (128 + ((pk >> 12) & 63)) * EMB + doff;
            for (int d = lane; d < 150; d += 64) {
                float m = hs[snode * 150 + d] + t0[d] + t1[d] + t2[d];
                m = fmaxf(m, 0.f);
                ag[dnode * 150 + d] += m;
            }
        }
        __syncthreads();
        for (int idx = tid; idx < 128 * 150; idx += 256) {
            const int i = idx / 150, d = idx - i * 150;
            h[(size_t)(g * 128 + i) * EMB + doff + d] = ag[idx];
        }
    }
}

// ---------------------------------------------------------------------------
// Kernel 3: bf16 MFMA GEMM  C[M,N] = A[M,K] @ B[K,N]
//   B pre-transposed bf16 [Npad][KP] (pad rows zero).
//   ABF16=1: A is bf16 [M][lda] (zero-padded K) -> global_load_lds staging.
//   ABF16=0: A is fp32 [M][lda], reg-stage + cvt, tail-masked at Kreal.
//   CBF16=1: C is bf16 [M][ldc] (pad cols written as 0); else fp32, n<Nreal.
//   Epilogue: v = gam*(acc+bias)+bet, optional relu.
// BM=128 BN=64 BK=32, 256 threads, 4 waves of 64x32 (4x2 16x16 frags).
// ---------------------------------------------------------------------------
template <int ABF16, int CBF16, int RELU>
__global__ __launch_bounds__(256)
void gemm_mfma(const void* __restrict__ Av, const int lda, const int Kreal,
               const int nT, const __bf16* __restrict__ B,
               void* __restrict__ Cv, const int ldc, const int Nreal,
               const float* __restrict__ bias, const float* __restrict__ gam,
               const float* __restrict__ bet)
{
    __shared__ unsigned short As[128 * 32];  // [m][k] bf16, 8 KB
    __shared__ unsigned short Bs[64 * 32];   // [n][k] bf16, 4 KB

    const int tid  = threadIdx.x;
    const int bn   = blockIdx.x * 64;
    const int bm   = blockIdx.y * 128;
    const int wid  = tid >> 6;
    const int lane = tid & 63;
    const int wm   = (wid >> 1) * 64;
    const int wn   = (wid & 1) * 32;
    const int lr   = lane & 15;
    const int kc   = (lane >> 4) * 8;
    const int KP   = nT * 32;

    f32x4 acc[4][2];
    #pragma unroll
    for (int mi = 0; mi < 4; ++mi)
        #pragma unroll
        for (int ni = 0; ni < 2; ++ni) acc[mi][ni] = (f32x4){0.f, 0.f, 0.f, 0.f};

    for (int t = 0; t < nT; ++t) {
        const int k0 = t * 32;
        // ---- B tile: 64 rows x 32 k bf16 = 4 KB, one gload/thread ----
        {
            const int n = tid >> 2, k8 = (tid & 3) * 8;
            gload_lds16(B + (size_t)(bn + n) * KP + k0 + k8,
                        (char*)Bs + tid * 16);
        }
        // ---- A tile: 128 rows x 32 k bf16 = 8 KB ----
        if (ABF16) {
            const __bf16* A = (const __bf16*)Av;
            #pragma unroll
            for (int q = 0; q < 2; ++q) {
                const int idx = q * 256 + tid;
                const int m = idx >> 2, k8 = (idx & 3) * 8;
                gload_lds16(A + (size_t)(bm + m) * lda + k0 + k8,
                            (char*)As + idx * 16);
            }
        } else {
            const float* A = (const float*)Av;
            #pragma unroll
            for (int q = 0; q < 2; ++q) {
                const int idx = q * 256 + tid;
                const int m = idx >> 2;
                const int k = k0 + (idx & 3) * 8;
                const float* src = A + (size_t)(bm + m) * lda + k;
                float v[8];
                if (k + 7 < Kreal) {
                    const float4 u0 = *(const float4*)src;
                    const float4 u1 = *(const float4*)(src + 4);
                    v[0] = u0.x; v[1] = u0.y; v[2] = u0.z; v[3] = u0.w;
                    v[4] = u1.x; v[5] = u1.y; v[6] = u1.z; v[7] = u1.w;
                } else {
                    #pragma unroll
                    for (int j = 0; j < 8; ++j) v[j] = (k + j < Kreal) ? src[j] : 0.f;
                }
                bf16x8 p;
                #pragma unroll
                for (int j = 0; j < 8; ++j) p[j] = (__bf16)v[j];
                *(bf16x8*)&As[idx * 8] = p;
            }
        }
        __syncthreads();

        bf16x8 a[4], bfr[2];
        #pragma unroll
        for (int mi = 0; mi < 4; ++mi)
            a[mi] = *(const bf16x8*)&As[(wm + mi * 16 + lr) * 32 + kc];
        #pragma unroll
        for (int ni = 0; ni < 2; ++ni)
            bfr[ni] = *(const bf16x8*)&Bs[(wn + ni * 16 + lr) * 32 + kc];
        #pragma unroll
        for (int mi = 0; mi < 4; ++mi)
            #pragma unroll
            for (int ni = 0; ni < 2; ++ni)
                acc[mi][ni] = __builtin_amdgcn_mfma_f32_16x16x32_bf16(
                    a[mi], bfr[ni], acc[mi][ni], 0, 0, 0);
        __syncthreads();
    }

    // ---- epilogue ----
    #pragma unroll
    for (int ni = 0; ni < 2; ++ni) {
        const int n = bn + wn + ni * 16 + lr;
        const bool nv = (n < Nreal);
        const float gv = nv ? gam[n]  : 0.f;
        const float bv = nv ? bias[n] : 0.f;
        const float ev = nv ? bet[n]  : 0.f;
        #pragma unroll
        for (int mi = 0; mi < 4; ++mi) {
            #pragma unroll
            for (int r = 0; r < 4; ++r) {
                const size_t m = bm + wm + mi * 16 + (lane >> 4) * 4 + r;
                float v = gv * (acc[mi][ni][r] + bv) + ev;
                if (RELU) v = fmaxf(v, 0.f);
                if (CBF16) {
                    ((__bf16*)Cv)[m * ldc + n] = (__bf16)v;   // pad cols -> 0
                } else if (nv) {
                    ((float*)Cv)[m * ldc + n] = v;
                }
            }
        }
    }
}

// ---------------------------------------------------------------------------
extern "C" void kernel_launch(void* const* d_in, const int* in_sizes, int n_in,
                              void* d_out, int out_size, void* d_ws, size_t ws_size,
                              hipStream_t stream)
{
    const int*   order_p       = (const int*)d_in[0];
    const int*   x_atom        = (const int*)d_in[1];
    const int*   edge_index    = (const int*)d_in[2];
    const int*   edge_attr     = (const int*)d_in[3];
    const float* atom_tab      = (const float*)d_in[4];
    const float* bond_tab_root = (const float*)d_in[5];
    const float* edge_lin_w    = (const float*)d_in[6];
    const float* edge_lin_b    = (const float*)d_in[7];
    const float* bond_tabs     = (const float*)d_in[8];
    const float* eps           = (const float*)d_in[9];
    const float* w1            = (const float*)d_in[10];
    const float* b1            = (const float*)d_in[11];
    const float* bn1g          = (const float*)d_in[12];
    const float* bn1b          = (const float*)d_in[13];
    const float* w2            = (const float*)d_in[14];
    const float* b2            = (const float*)d_in[15];
    const float* bng           = (const float*)d_in[16];
    const float* bnb           = (const float*)d_in[17];

    float* h = (float*)d_out;   // [65536][300] fp32 master activations

    // workspace layout
    char* ws = (char*)d_ws;
    __bf16* z1  = (__bf16*)ws;                                  // [65536][640] = 83,886,080 B
    __bf16* w1t = (__bf16*)(ws + 83886080);                     // [5][640][320] = 2,048,000 B
    __bf16* w2t = (__bf16*)(ws + 83886080 + 2048000);           // [5][320][640] = 2,048,000 B

    prep_w_kernel<<<8000, 256, 0, stream>>>(w1, w2, w1t, w2t);

    diffuse_kernel<<<NGRAPH, 256, 0, stream>>>(order_p, x_atom, edge_index, edge_attr,
                                               atom_tab, bond_tab_root, edge_lin_w,
                                               edge_lin_b, h);

    for (int l = 0; l < NLAYER; ++l) {
        agg_kernel<<<NGRAPH, 256, 0, stream>>>(edge_index, edge_attr, bond_tabs, eps, l, h);

        // gemm1: z1[65536,640bf16] = relu(bn1(h @ w1 + b1)); K=300 (pad 320)
        gemm_mfma<0, 1, 1><<<dim3(10, 512), 256, 0, stream>>>(
            h, EMB, 300, 10, w1t + (size_t)l * 640 * 320,
            z1, 640, 600, b1 + l * 600, bn1g + l * 600, bn1b + l * 600);

        // gemm2: h[65536,300fp32] = bn(z1 @ w2 + b2), relu except last; K=640 padded
        if (l < NLAYER - 1) {
            gemm_mfma<1, 0, 1><<<dim3(5, 512), 256, 0, stream>>>(
                z1, 640, 640, 20, w2t + (size_t)l * 320 * 640,
                h, EMB, 300, b2 + l * 300, bng + l * 300, bnb + l * 300);
        } else {
            gemm_mfma<1, 0, 0><<<dim3(5, 512), 256, 0, stream>>>(
                z1, 640, 640, 20, w2t + (size_t)l * 320 * 640,
                h, EMB, 300, b2 + l * 300, bng + l * 300, bnb + l * 300);
        }
    }
}

// Round 3
// 2544.083 us; speedup vs baseline: 2.5287x; 1.7028x over previous
//
#include <hip/hip_runtime.h>

#define NGRAPH 512
#define NNODE  128
#define NEDGE  512
#define EMB    300
#define NLAYER 5
#define FA     9
#define FB     3
#define VV     64

typedef __bf16 bf16x8 __attribute__((ext_vector_type(8)));
typedef float  f32x4  __attribute__((ext_vector_type(4)));

__device__ __forceinline__ void gload_lds16(const void* gptr, void* lptr) {
    __builtin_amdgcn_global_load_lds(
        (const __attribute__((address_space(1))) void*)gptr,
        (__attribute__((address_space(3))) void*)lptr, 16, 0, 0);
}

// ---------------------------------------------------------------------------
// Kernel 0: weight prep — transpose w1/w2 to bf16 [N][K], K padded to x32,
// N padded to the 64-wide GEMM block grid (pad rows/cols zeroed).
// w1t: [L][640][320]  (real 600 x 300);  w2t: [L][320][640] (real 300 x 600)
// ---------------------------------------------------------------------------
__global__ __launch_bounds__(256)
void prep_w_kernel(const float* __restrict__ w1, const float* __restrict__ w2,
                   __bf16* __restrict__ w1t, __bf16* __restrict__ w2t)
{
    const int i = blockIdx.x * 256 + threadIdx.x;
    const int T1 = NLAYER * 640 * 320;
    const int T2 = NLAYER * 320 * 640;
    if (i < T1) {
        const int l = i / (640 * 320);
        const int r = i - l * 640 * 320;
        const int n = r / 320, k = r - n * 320;
        float v = (n < 600 && k < 300) ? w1[((size_t)l * 300 + k) * 600 + n] : 0.f;
        w1t[i] = (__bf16)v;
    } else if (i < T1 + T2) {
        const int j = i - T1;
        const int l = j / (320 * 640);
        const int r = j - l * 320 * 640;
        const int n = r / 640, k = r - n * 640;
        float v = (n < 300 && k < 600) ? w2[((size_t)l * 600 + k) * 300 + n] : 0.f;
        w2t[j] = (__bf16)v;
    }
}

// ---------------------------------------------------------------------------
// Kernel 1: atom encode + edge weights + dense normalized-adjacency diffusion
// (unchanged)
// ---------------------------------------------------------------------------
__global__ __launch_bounds__(256)
void diffuse_kernel(const int* __restrict__ order_p,
                    const int* __restrict__ x_atom,
                    const int* __restrict__ edge_index,
                    const int* __restrict__ edge_attr,
                    const float* __restrict__ atom_tab,
                    const float* __restrict__ bond_tab_root,
                    const float* __restrict__ edge_lin_w,
                    const float* __restrict__ edge_lin_b,
                    float* __restrict__ h)
{
    __shared__ float A[128 * 129];
    __shared__ float xb[2 * 128 * 68];
    __shared__ float ew_s[NEDGE];
    __shared__ int   es[NEDGE];
    __shared__ int   xat[128 * FA];
    __shared__ float rinv[128];
    __shared__ float cinv[128];

    const int tid = threadIdx.x;
    const int g   = blockIdx.x;

    for (int e = tid; e < NEDGE; e += 256) {
        int r = edge_index[(g * 2 + 0) * NEDGE + e];
        int c = edge_index[(g * 2 + 1) * NEDGE + e];
        es[e] = r | (c << 8);
    }
    for (int i = tid; i < 128 * FA; i += 256) xat[i] = x_atom[g * 128 * FA + i];
    int* prio = (int*)xb;
    for (int i = tid; i < 128 * 129; i += 256) A[i] = 0.f;
    for (int i = tid; i < 128 * 128; i += 256) prio[i] = -1;
    __syncthreads();

    {
        const int wave = tid >> 6, lane = tid & 63;
        const float elb = edge_lin_b[0];
        for (int e = wave * 128; e < wave * 128 + 128; ++e) {
            const int base = (g * NEDGE + e) * 3;
            const int a0 = edge_attr[base + 0];
            const int a1 = edge_attr[base + 1];
            const int a2 = edge_attr[base + 2];
            const float* t0 = bond_tab_root + (0 * VV + a0) * EMB;
            const float* t1 = bond_tab_root + (1 * VV + a1) * EMB;
            const float* t2 = bond_tab_root + (2 * VV + a2) * EMB;
            float acc = 0.f;
            for (int d = lane; d < EMB; d += 64)
                acc += (t0[d] + t1[d] + t2[d]) * edge_lin_w[d];
            #pragma unroll
            for (int off = 32; off > 0; off >>= 1) acc += __shfl_xor(acc, off, 64);
            if (lane == 0) ew_s[e] = 1.f / (1.f + expf(-(acc + elb)));
        }
    }
    __syncthreads();

    for (int e = tid; e < NEDGE; e += 256) {
        int r = es[e] & 255, c = es[e] >> 8;
        atomicMax(&prio[r * 128 + c], e);
        atomicMax(&prio[c * 128 + r], 512 + e);
    }
    __syncthreads();
    for (int e = tid; e < NEDGE; e += 256) {
        int r = es[e] & 255, c = es[e] >> 8;
        if (prio[r * 128 + c] == e)       A[r * 129 + c] = ew_s[e];
        if (prio[c * 128 + r] == 512 + e) A[c * 129 + r] = ew_s[e];
    }
    __syncthreads();
    if (tid < 128) A[tid * 129 + tid] += 1.f;
    __syncthreads();
    if (tid < 128) {
        float rs = 0.f, cs = 0.f;
        for (int j = 0; j < 128; ++j) { rs += A[tid * 129 + j]; cs += A[j * 129 + tid]; }
        rinv[tid] = 1.f / sqrtf(rs);
        cinv[tid] = 1.f / sqrtf(cs);
    }
    __syncthreads();
    for (int i = tid; i < 128 * 128; i += 256) {
        int r = i >> 7, c = i & 127;
        A[r * 129 + c] *= cinv[r] * rinv[c];
    }

    const int   ord    = order_p[0];
    const float yscale = 1.f / (float)(ord + 1);
    const int rg = tid >> 3, dg = tid & 7;
    const int i0 = rg * 4, d0 = dg * 8;
    float* x0 = xb;
    float* x1 = xb + 128 * 68;

    for (int cb = 0; cb < 5; ++cb) {
        const int dbase = cb * 64;
        __syncthreads();

        float y[4][8];
        #pragma unroll
        for (int ii = 0; ii < 4; ++ii)
            #pragma unroll
            for (int dd = 0; dd < 8; ++dd) y[ii][dd] = 0.f;
        #pragma unroll
        for (int f = 0; f < FA; ++f) {
            #pragma unroll
            for (int ii = 0; ii < 4; ++ii) {
                const int idx = xat[(i0 + ii) * FA + f];
                const float* row = atom_tab + (size_t)(f * VV + idx) * EMB + dbase + d0;
                #pragma unroll
                for (int dd = 0; dd < 8; ++dd)
                    if (dbase + d0 + dd < EMB) y[ii][dd] += row[dd];
            }
        }
        #pragma unroll
        for (int ii = 0; ii < 4; ++ii)
            #pragma unroll
            for (int dd = 0; dd < 8; ++dd) {
                y[ii][dd] *= 0.8f;
                x0[(i0 + ii) * 68 + d0 + dd] = y[ii][dd];
            }
        float* cur = x0;
        float* nxt = x1;
        __syncthreads();

        for (int o = 0; o < ord; ++o) {
            float r[4][8];
            #pragma unroll
            for (int ii = 0; ii < 4; ++ii)
                #pragma unroll
                for (int dd = 0; dd < 8; ++dd) r[ii][dd] = 0.f;
            for (int j = 0; j < 128; ++j) {
                const float a0 = A[(i0 + 0) * 129 + j];
                const float a1 = A[(i0 + 1) * 129 + j];
                const float a2 = A[(i0 + 2) * 129 + j];
                const float a3 = A[(i0 + 3) * 129 + j];
                const float* xr = &cur[j * 68 + d0];
                const float4 xv0 = *(const float4*)&xr[0];
                const float4 xv1 = *(const float4*)&xr[4];
                const float xv[8] = {xv0.x, xv0.y, xv0.z, xv0.w,
                                     xv1.x, xv1.y, xv1.z, xv1.w};
                #pragma unroll
                for (int dd = 0; dd < 8; ++dd) {
                    r[0][dd] += a0 * xv[dd];
                    r[1][dd] += a1 * xv[dd];
                    r[2][dd] += a2 * xv[dd];
                    r[3][dd] += a3 * xv[dd];
                }
            }
            #pragma unroll
            for (int ii = 0; ii < 4; ++ii)
                #pragma unroll
                for (int dd = 0; dd < 8; ++dd) {
                    nxt[(i0 + ii) * 68 + d0 + dd] = r[ii][dd];
                    y[ii][dd] += r[ii][dd];
                }
            __syncthreads();
            float* t = cur; cur = nxt; nxt = t;
        }

        #pragma unroll
        for (int ii = 0; ii < 4; ++ii) {
            float* hrow = h + (size_t)(g * 128 + i0 + ii) * EMB + dbase + d0;
            #pragma unroll
            for (int dd = 0; dd < 8; ++dd)
                if (dbase + d0 + dd < EMB) hrow[dd] = y[ii][dd] * yscale;
        }
    }
}

// ---------------------------------------------------------------------------
// Kernel 2: GIN aggregation, CSR gather version.
// One block (1024 thr, 16 waves) per graph. CSR built in LDS; each wave owns
// nodes n%16==wave; per-node accumulation in registers; h[src] read from an
// LDS snapshot (pre-update values), dims in 2 halves of 150.
// h <- (1+eps)h + sum_in relu(h[src] + ee)
// ---------------------------------------------------------------------------
__global__ __launch_bounds__(1024)
void agg_kernel(const int* __restrict__ edge_index,
                const int* __restrict__ edge_attr,
                const float* __restrict__ bond_tabs,
                const float* __restrict__ eps_all,
                const int l,
                float* __restrict__ h)
{
    __shared__ float hs[128 * 152];   // 77,824 B snapshot (stride 152, conflict-free)
    __shared__ int   es[NEDGE];       // src | dst<<8
    __shared__ int   eas[NEDGE];      // a0 | a1<<6 | a2<<12
    __shared__ int   eord[NEDGE];     // edge ids sorted by dst
    __shared__ int   cnt[128];
    __shared__ int   off_[129];
    __shared__ int   fill[128];

    const int tid = threadIdx.x;
    const int g   = blockIdx.x;
    const float epl = 1.f + eps_all[l];
    const float* bt = bond_tabs + (size_t)l * FB * VV * EMB;

    if (tid < 128) { cnt[tid] = 0; fill[tid] = 0; }
    __syncthreads();
    if (tid < NEDGE) {
        const int s_ = edge_index[(g * 2 + 0) * NEDGE + tid];
        const int d_ = edge_index[(g * 2 + 1) * NEDGE + tid];
        es[tid] = s_ | (d_ << 8);
        const int base = (g * NEDGE + tid) * 3;
        eas[tid] = edge_attr[base + 0] | (edge_attr[base + 1] << 6) | (edge_attr[base + 2] << 12);
        atomicAdd(&cnt[d_], 1);
    }
    __syncthreads();
    // exclusive prefix scan of cnt[128] on wave 0
    if (tid < 64) {
        const int a = cnt[tid];
        const int b = cnt[64 + tid];
        int ia = a;
        #pragma unroll
        for (int o = 1; o < 64; o <<= 1) {
            int t = __shfl_up(ia, o, 64);
            if (tid >= o) ia += t;
        }
        const int totA = __shfl(ia, 63, 64);
        int ib = b;
        #pragma unroll
        for (int o = 1; o < 64; o <<= 1) {
            int t = __shfl_up(ib, o, 64);
            if (tid >= o) ib += t;
        }
        off_[tid]      = ia - a;
        off_[64 + tid] = totA + ib - b;
        if (tid == 63) off_[128] = totA + ib;
    }
    __syncthreads();
    if (tid < NEDGE) {
        const int d_ = es[tid] >> 8;
        const int pos = off_[d_] + atomicAdd(&fill[d_], 1);
        eord[pos] = tid;
    }

    const int wave = tid >> 6, lane = tid & 63;
    const int d0 = lane, d1 = lane + 64, d2 = lane + 128;

    for (int half = 0; half < 2; ++half) {
        const int doff = half * 150;
        __syncthreads();   // eord ready / previous half's readers done with hs
        for (int idx = tid; idx < 128 * 150; idx += 1024) {
            const int i = idx / 150, d = idx - i * 150;
            hs[i * 152 + d] = h[(size_t)(g * 128 + i) * EMB + doff + d];
        }
        __syncthreads();
        for (int n = wave; n < 128; n += 16) {
            float acc0 = epl * hs[n * 152 + d0];
            float acc1 = (d1 < 150) ? epl * hs[n * 152 + d1] : 0.f;
            float acc2 = (d2 < 150) ? epl * hs[n * 152 + d2] : 0.f;
            const int eBeg = off_[n], eEnd = off_[n + 1];
            for (int ee = eBeg; ee < eEnd; ++ee) {
                const int e   = eord[ee];
                const int src = es[e] & 255;
                const int pk  = eas[e];
                const float* t0 = bt + ((pk) & 63) * EMB + doff;
                const float* t1 = bt + (64  + ((pk >> 6)  & 63)) * EMB + doff;
                const float* t2 = bt + (128 + ((pk >> 12) & 63)) * EMB + doff;
                acc0 += fmaxf(hs[src * 152 + d0] + t0[d0] + t1[d0] + t2[d0], 0.f);
                if (d1 < 150)
                    acc1 += fmaxf(hs[src * 152 + d1] + t0[d1] + t1[d1] + t2[d1], 0.f);
                if (d2 < 150)
                    acc2 += fmaxf(hs[src * 152 + d2] + t0[d2] + t1[d2] + t2[d2], 0.f);
            }
            float* hrow = h + (size_t)(g * 128 + n) * EMB + doff;
            hrow[d0] = acc0;
            if (d1 < 150) hrow[d1] = acc1;
            if (d2 < 150) hrow[d2] = acc2;
        }
    }
}

// ---------------------------------------------------------------------------
// Kernel 3: bf16 MFMA GEMM (unchanged)
// ---------------------------------------------------------------------------
template <int ABF16, int CBF16, int RELU>
__global__ __launch_bounds__(256)
void gemm_mfma(const void* __restrict__ Av, const int lda, const int Kreal,
               const int nT, const __bf16* __restrict__ B,
               void* __restrict__ Cv, const int ldc, const int Nreal,
               const float* __restrict__ bias, const float* __restrict__ gam,
               const float* __restrict__ bet)
{
    __shared__ unsigned short As[128 * 32];
    __shared__ unsigned short Bs[64 * 32];

    const int tid  = threadIdx.x;
    const int bn   = blockIdx.x * 64;
    const int bm   = blockIdx.y * 128;
    const int wid  = tid >> 6;
    const int lane = tid & 63;
    const int wm   = (wid >> 1) * 64;
    const int wn   = (wid & 1) * 32;
    const int lr   = lane & 15;
    const int kc   = (lane >> 4) * 8;
    const int KP   = nT * 32;

    f32x4 acc[4][2];
    #pragma unroll
    for (int mi = 0; mi < 4; ++mi)
        #pragma unroll
        for (int ni = 0; ni < 2; ++ni) acc[mi][ni] = (f32x4){0.f, 0.f, 0.f, 0.f};

    for (int t = 0; t < nT; ++t) {
        const int k0 = t * 32;
        {
            const int n = tid >> 2, k8 = (tid & 3) * 8;
            gload_lds16(B + (size_t)(bn + n) * KP + k0 + k8,
                        (char*)Bs + tid * 16);
        }
        if (ABF16) {
            const __bf16* A = (const __bf16*)Av;
            #pragma unroll
            for (int q = 0; q < 2; ++q) {
                const int idx = q * 256 + tid;
                const int m = idx >> 2, k8 = (idx & 3) * 8;
                gload_lds16(A + (size_t)(bm + m) * lda + k0 + k8,
                            (char*)As + idx * 16);
            }
        } else {
            const float* A = (const float*)Av;
            #pragma unroll
            for (int q = 0; q < 2; ++q) {
                const int idx = q * 256 + tid;
                const int m = idx >> 2;
                const int k = k0 + (idx & 3) * 8;
                const float* src = A + (size_t)(bm + m) * lda + k;
                float v[8];
                if (k + 7 < Kreal) {
                    const float4 u0 = *(const float4*)src;
                    const float4 u1 = *(const float4*)(src + 4);
                    v[0] = u0.x; v[1] = u0.y; v[2] = u0.z; v[3] = u0.w;
                    v[4] = u1.x; v[5] = u1.y; v[6] = u1.z; v[7] = u1.w;
                } else {
                    #pragma unroll
                    for (int j = 0; j < 8; ++j) v[j] = (k + j < Kreal) ? src[j] : 0.f;
                }
                bf16x8 p;
                #pragma unroll
                for (int j = 0; j < 8; ++j) p[j] = (__bf16)v[j];
                *(bf16x8*)&As[idx * 8] = p;
            }
        }
        __syncthreads();

        bf16x8 a[4], bfr[2];
        #pragma unroll
        for (int mi = 0; mi < 4; ++mi)
            a[mi] = *(const bf16x8*)&As[(wm + mi * 16 + lr) * 32 + kc];
        #pragma unroll
        for (int ni = 0; ni < 2; ++ni)
            bfr[ni] = *(const bf16x8*)&Bs[(wn + ni * 16 + lr) * 32 + kc];
        #pragma unroll
        for (int mi = 0; mi < 4; ++mi)
            #pragma unroll
            for (int ni = 0; ni < 2; ++ni)
                acc[mi][ni] = __builtin_amdgcn_mfma_f32_16x16x32_bf16(
                    a[mi], bfr[ni], acc[mi][ni], 0, 0, 0);
        __syncthreads();
    }

    #pragma unroll
    for (int ni = 0; ni < 2; ++ni) {
        const int n = bn + wn + ni * 16 + lr;
        const bool nv = (n < Nreal);
        const float gv = nv ? gam[n]  : 0.f;
        const float bv = nv ? bias[n] : 0.f;
        const float ev = nv ? bet[n]  : 0.f;
        #pragma unroll
        for (int mi = 0; mi < 4; ++mi) {
            #pragma unroll
            for (int r = 0; r < 4; ++r) {
                const size_t m = bm + wm + mi * 16 + (lane >> 4) * 4 + r;
                float v = gv * (acc[mi][ni][r] + bv) + ev;
                if (RELU) v = fmaxf(v, 0.f);
                if (CBF16) {
                    ((__bf16*)Cv)[m * ldc + n] = (__bf16)v;
                } else if (nv) {
                    ((float*)Cv)[m * ldc + n] = v;
                }
            }
        }
    }
}

// ---------------------------------------------------------------------------
extern "C" void kernel_launch(void* const* d_in, const int* in_sizes, int n_in,
                              void* d_out, int out_size, void* d_ws, size_t ws_size,
                              hipStream_t stream)
{
    const int*   order_p       = (const int*)d_in[0];
    const int*   x_atom        = (const int*)d_in[1];
    const int*   edge_index    = (const int*)d_in[2];
    const int*   edge_attr     = (const int*)d_in[3];
    const float* atom_tab      = (const float*)d_in[4];
    const float* bond_tab_root = (const float*)d_in[5];
    const float* edge_lin_w    = (const float*)d_in[6];
    const float* edge_lin_b    = (const float*)d_in[7];
    const float* bond_tabs     = (const float*)d_in[8];
    const float* eps           = (const float*)d_in[9];
    const float* w1            = (const float*)d_in[10];
    const float* b1            = (const float*)d_in[11];
    const float* bn1g          = (const float*)d_in[12];
    const float* bn1b          = (const float*)d_in[13];
    const float* w2            = (const float*)d_in[14];
    const float* b2            = (const float*)d_in[15];
    const float* bng           = (const float*)d_in[16];
    const float* bnb           = (const float*)d_in[17];

    float* h = (float*)d_out;   // [65536][300] fp32 master activations

    char* ws = (char*)d_ws;
    __bf16* z1  = (__bf16*)ws;                                  // [65536][640]
    __bf16* w1t = (__bf16*)(ws + 83886080);                     // [5][640][320]
    __bf16* w2t = (__bf16*)(ws + 83886080 + 2048000);           // [5][320][640]

    prep_w_kernel<<<8000, 256, 0, stream>>>(w1, w2, w1t, w2t);

    diffuse_kernel<<<NGRAPH, 256, 0, stream>>>(order_p, x_atom, edge_index, edge_attr,
                                               atom_tab, bond_tab_root, edge_lin_w,
                                               edge_lin_b, h);

    for (int l = 0; l < NLAYER; ++l) {
        agg_kernel<<<NGRAPH, 1024, 0, stream>>>(edge_index, edge_attr, bond_tabs, eps, l, h);

        gemm_mfma<0, 1, 1><<<dim3(10, 512), 256, 0, stream>>>(
            h, EMB, 300, 10, w1t + (size_t)l * 640 * 320,
            z1, 640, 600, b1 + l * 600, bn1g + l * 600, bn1b + l * 600);

        if (l < NLAYER - 1) {
            gemm_mfma<1, 0, 1><<<dim3(5, 512), 256, 0, stream>>>(
                z1, 640, 640, 20, w2t + (size_t)l * 320 * 640,
                h, EMB, 300, b2 + l * 300, bng + l * 300, bnb + l * 300);
        } else {
            gemm_mfma<1, 0, 0><<<dim3(5, 512), 256, 0, stream>>>(
                z1, 640, 640, 20, w2t + (size_t)l * 320 * 640,
                h, EMB, 300, b2 + l * 300, bng + l * 300, bnb + l * 300);
        }
    }
}

// Round 5
// 1942.442 us; speedup vs baseline: 3.3120x; 1.3097x over previous
//
#include <hip/hip_runtime.h>

#define NGRAPH 512
#define NNODE  128
#define NEDGE  512
#define EMB    300
#define NLAYER 5
#define FA     9
#define FB     3
#define VV     64
#define KPAD   136   // padded K stride (bf16 elems) for A / xT tiles

typedef __bf16 bf16x8 __attribute__((ext_vector_type(8)));
typedef __bf16 bf16x4 __attribute__((ext_vector_type(4)));
typedef float  f32x4  __attribute__((ext_vector_type(4)));

__device__ __forceinline__ void gload_lds16(const void* gptr, void* lptr) {
    __builtin_amdgcn_global_load_lds(
        (const __attribute__((address_space(1))) void*)gptr,
        (__attribute__((address_space(3))) void*)lptr, 16, 0, 0);
}

// ---------------------------------------------------------------------------
// Kernel 0: weight prep — transpose w1/w2 to bf16 [N][K] (padded, zeros).
// ---------------------------------------------------------------------------
__global__ __launch_bounds__(256)
void prep_w_kernel(const float* __restrict__ w1, const float* __restrict__ w2,
                   __bf16* __restrict__ w1t, __bf16* __restrict__ w2t)
{
    const int i = blockIdx.x * 256 + threadIdx.x;
    const int T1 = NLAYER * 640 * 320;
    const int T2 = NLAYER * 320 * 640;
    if (i < T1) {
        const int l = i / (640 * 320);
        const int r = i - l * 640 * 320;
        const int n = r / 320, k = r - n * 320;
        float v = (n < 600 && k < 300) ? w1[((size_t)l * 300 + k) * 600 + n] : 0.f;
        w1t[i] = (__bf16)v;
    } else if (i < T1 + T2) {
        const int j = i - T1;
        const int l = j / (320 * 640);
        const int r = j - l * 320 * 640;
        const int n = r / 640, k = r - n * 640;
        float v = (n < 300 && k < 600) ? w2[((size_t)l * 600 + k) * 300 + n] : 0.f;
        w2t[j] = (__bf16)v;
    }
}

// ---------------------------------------------------------------------------
// Kernel 1a: adjacency build — edge weights, last-wins scatter (prio in-place
// in A's int view), symmetric normalization; export split-bf16 A (hi+lo),
// padded [128][KPAD], pad zeroed.
// ---------------------------------------------------------------------------
__global__ __launch_bounds__(512)
void adj_kernel(const int* __restrict__ edge_index,
                const int* __restrict__ edge_attr,
                const float* __restrict__ bond_tab_root,
                const float* __restrict__ edge_lin_w,
                const float* __restrict__ edge_lin_b,
                __bf16* __restrict__ Ahi_g, __bf16* __restrict__ Alo_g)
{
    __shared__ float A[128 * 129];     // int view during prio phase
    __shared__ float ew_s[NEDGE];
    __shared__ int   es[NEDGE];
    __shared__ float rinv[128];
    __shared__ float cinv[128];

    const int tid = threadIdx.x;
    const int g   = blockIdx.x;
    int* Ai = (int*)A;

    for (int e = tid; e < NEDGE; e += 512) {
        int r = edge_index[(g * 2 + 0) * NEDGE + e];
        int c = edge_index[(g * 2 + 1) * NEDGE + e];
        es[e] = r | (c << 8);
    }
    for (int i = tid; i < 128 * 129; i += 512) Ai[i] = -1;
    __syncthreads();

    // edge weights: ew = sigmoid(e_emb . w + b); wave w handles edges [64w,64w+64)
    {
        const int wave = tid >> 6, lane = tid & 63;
        const float elb = edge_lin_b[0];
        for (int e = wave * 64; e < wave * 64 + 64; ++e) {
            const int base = (g * NEDGE + e) * 3;
            const int a0 = edge_attr[base + 0];
            const int a1 = edge_attr[base + 1];
            const int a2 = edge_attr[base + 2];
            const float* t0 = bond_tab_root + (0 * VV + a0) * EMB;
            const float* t1 = bond_tab_root + (1 * VV + a1) * EMB;
            const float* t2 = bond_tab_root + (2 * VV + a2) * EMB;
            float acc = 0.f;
            for (int d = lane; d < EMB; d += 64)
                acc += (t0[d] + t1[d] + t2[d]) * edge_lin_w[d];
            #pragma unroll
            for (int off = 32; off > 0; off >>= 1) acc += __shfl_xor(acc, off, 64);
            if (lane == 0) ew_s[e] = 1.f / (1.f + expf(-(acc + elb)));
        }
    }
    // last-wins scatter via max-priority (phase-1 = e, phase-2 = 512+e)
    for (int e = tid; e < NEDGE; e += 512) {
        int r = es[e] & 255, c = es[e] >> 8;
        atomicMax(&Ai[r * 129 + c], e);
        atomicMax(&Ai[c * 129 + r], 512 + e);
    }
    __syncthreads();
    for (int i = tid; i < 128 * 129; i += 512) {
        int p = Ai[i];
        A[i] = (p < 0) ? 0.f : ew_s[p & 511];
    }
    __syncthreads();
    if (tid < 128) A[tid * 129 + tid] += 1.f;
    __syncthreads();
    if (tid < 128) {
        float rs = 0.f, cs = 0.f;
        for (int j = 0; j < 128; ++j) { rs += A[tid * 129 + j]; cs += A[j * 129 + tid]; }
        rinv[tid] = 1.f / sqrtf(rs);   // from row sums -> applied on column index
        cinv[tid] = 1.f / sqrtf(cs);   // from col sums -> applied on row index
    }
    __syncthreads();
    for (int i = tid; i < 128 * KPAD; i += 512) {
        const int m = i / KPAD, k = i - m * KPAD;
        float v = (k < 128) ? A[m * 129 + k] * cinv[m] * rinv[k] : 0.f;
        __bf16 hi = (__bf16)v;
        Ahi_g[(size_t)g * 128 * KPAD + i] = hi;
        Alo_g[(size_t)g * 128 * KPAD + i] = (__bf16)(v - (float)hi);
    }
}

// ---------------------------------------------------------------------------
// Kernel 1b: diffusion via MFMA with split-bf16 (hi/lo) ~fp32 precision.
// One block (512 thr, 8 waves) per graph. Per 64-dim chunk: fp32 encode ->
// split xT[n][k]; ord hops of r = A@x as Ahi*xhi + Ahi*xlo + Alo*xhi;
// y accumulated in fp32; h = y/(ord+1).
// ---------------------------------------------------------------------------
__global__ __launch_bounds__(512)
void diffuse_mm_kernel(const int* __restrict__ order_p,
                       const int* __restrict__ x_atom,
                       const float* __restrict__ atom_tab,
                       const __bf16* __restrict__ Ahi_g,
                       const __bf16* __restrict__ Alo_g,
                       float* __restrict__ h)
{
    __shared__ __bf16 Ahi[128 * KPAD];        // 34,816 B
    __shared__ __bf16 Alo[128 * KPAD];        // 34,816 B
    __shared__ __bf16 xt[4 * 64 * KPAD];      // 69,632 B: [buf*2 + (0=hi,1=lo)][n][k]
    __shared__ int    xat[128 * FA];          // 4,608 B

    const int tid  = threadIdx.x;
    const int g    = blockIdx.x;
    const int lane = tid & 63;
    const int wid  = tid >> 6;
    const int wm   = (wid >> 1) * 32;     // wave's 32-row M tile
    const int wn   = (wid & 1) * 32;      // wave's 32-col N (dim) tile
    const int lr   = lane & 15;
    const int q4   = (lane >> 4) * 4;     // C-frag row group
    const int kc   = (lane >> 4) * 8;     // A/B-frag k offset

    // stage split A (linear, layout == global) + atom indices
    for (int idx = tid; idx < 128 * KPAD / 8; idx += 512) {
        gload_lds16(Ahi_g + (size_t)g * 128 * KPAD + idx * 8, (char*)Ahi + idx * 16);
        gload_lds16(Alo_g + (size_t)g * 128 * KPAD + idx * 8, (char*)Alo + idx * 16);
    }
    for (int i = tid; i < 128 * FA; i += 512) xat[i] = x_atom[g * 128 * FA + i];
    __syncthreads();   // xat visible to ALL waves before encode reads it
                       // (also drains the A-staging vmcnt before first hop)

    const int   ord    = order_p[0];
    const float yscale = 1.f / (float)(ord + 1);

    for (int cb = 0; cb < 5; ++cb) {
        const int dbase = cb * 64;

        // ---- encode chunk in fp32, split to xT buf0, seed y ----
        float yacc[2][2][4];
        #pragma unroll
        for (int mi = 0; mi < 2; ++mi) {
            #pragma unroll
            for (int ni = 0; ni < 2; ++ni) {
                const int n_ = wn + ni * 16 + lr;
                const int d  = dbase + n_;
                #pragma unroll
                for (int r = 0; r < 4; ++r) {
                    const int m_ = wm + mi * 16 + q4 + r;
                    float v = 0.f;
                    if (d < EMB) {
                        #pragma unroll
                        for (int f = 0; f < FA; ++f)
                            v += atom_tab[(size_t)((f << 6) + xat[m_ * FA + f]) * EMB + d];
                        v *= 0.8f;
                    }
                    yacc[mi][ni][r] = v;
                    __bf16 hi = (__bf16)v;
                    xt[0 * 64 * KPAD + n_ * KPAD + m_] = hi;
                    xt[1 * 64 * KPAD + n_ * KPAD + m_] = (__bf16)(v - (float)hi);
                }
            }
        }
        __syncthreads();   // xT buf0 ready

        int curbuf = 0;
        for (int o = 0; o < ord; ++o) {
            const __bf16* xh = xt + (curbuf * 2 + 0) * 64 * KPAD;
            const __bf16* xl = xt + (curbuf * 2 + 1) * 64 * KPAD;
            f32x4 racc[2][2];
            #pragma unroll
            for (int mi = 0; mi < 2; ++mi)
                #pragma unroll
                for (int ni = 0; ni < 2; ++ni) racc[mi][ni] = (f32x4){0.f, 0.f, 0.f, 0.f};

            #pragma unroll
            for (int ks = 0; ks < 4; ++ks) {
                const int k0 = ks * 32 + kc;
                bf16x8 ah[2], al[2], bh[2], bl[2];
                #pragma unroll
                for (int mi = 0; mi < 2; ++mi) {
                    ah[mi] = *(const bf16x8*)&Ahi[(wm + mi * 16 + lr) * KPAD + k0];
                    al[mi] = *(const bf16x8*)&Alo[(wm + mi * 16 + lr) * KPAD + k0];
                }
                #pragma unroll
                for (int ni = 0; ni < 2; ++ni) {
                    bh[ni] = *(const bf16x8*)&xh[(wn + ni * 16 + lr) * KPAD + k0];
                    bl[ni] = *(const bf16x8*)&xl[(wn + ni * 16 + lr) * KPAD + k0];
                }
                #pragma unroll
                for (int mi = 0; mi < 2; ++mi) {
                    #pragma unroll
                    for (int ni = 0; ni < 2; ++ni) {
                        racc[mi][ni] = __builtin_amdgcn_mfma_f32_16x16x32_bf16(
                            ah[mi], bh[ni], racc[mi][ni], 0, 0, 0);
                        racc[mi][ni] = __builtin_amdgcn_mfma_f32_16x16x32_bf16(
                            ah[mi], bl[ni], racc[mi][ni], 0, 0, 0);
                        racc[mi][ni] = __builtin_amdgcn_mfma_f32_16x16x32_bf16(
                            al[mi], bh[ni], racc[mi][ni], 0, 0, 0);
                    }
                }
            }

            // write r into the other buffer (split), accumulate y
            __bf16* nh = xt + ((curbuf ^ 1) * 2 + 0) * 64 * KPAD;
            __bf16* nl = xt + ((curbuf ^ 1) * 2 + 1) * 64 * KPAD;
            #pragma unroll
            for (int mi = 0; mi < 2; ++mi) {
                #pragma unroll
                for (int ni = 0; ni < 2; ++ni) {
                    const int n_ = wn + ni * 16 + lr;
                    const int mbase = wm + mi * 16 + q4;
                    bf16x4 hv, lv;
                    #pragma unroll
                    for (int r = 0; r < 4; ++r) {
                        const float v = racc[mi][ni][r];
                        yacc[mi][ni][r] += v;
                        __bf16 hi = (__bf16)v;
                        hv[r] = hi;
                        lv[r] = (__bf16)(v - (float)hi);
                    }
                    *(bf16x4*)&nh[n_ * KPAD + mbase] = hv;
                    *(bf16x4*)&nl[n_ * KPAD + mbase] = lv;
                }
            }
            __syncthreads();
            curbuf ^= 1;
        }

        // ---- h write: y / (ord+1) ----
        #pragma unroll
        for (int mi = 0; mi < 2; ++mi) {
            #pragma unroll
            for (int ni = 0; ni < 2; ++ni) {
                const int n_ = wn + ni * 16 + lr;
                const int d  = dbase + n_;
                if (d < EMB) {
                    #pragma unroll
                    for (int r = 0; r < 4; ++r) {
                        const int m_ = wm + mi * 16 + q4 + r;
                        h[(size_t)(g * 128 + m_) * EMB + d] = yacc[mi][ni][r] * yscale;
                    }
                }
            }
        }
        // next chunk's encode only writes buf0 slots after the final hop
        // barrier; all xt readers passed that barrier already.
    }
}

// ---------------------------------------------------------------------------
// Kernel 2: GIN aggregation, CSR gather version (unchanged).
// ---------------------------------------------------------------------------
__global__ __launch_bounds__(1024)
void agg_kernel(const int* __restrict__ edge_index,
                const int* __restrict__ edge_attr,
                const float* __restrict__ bond_tabs,
                const float* __restrict__ eps_all,
                const int l,
                float* __restrict__ h)
{
    __shared__ float hs[128 * 152];
    __shared__ int   es[NEDGE];
    __shared__ int   eas[NEDGE];
    __shared__ int   eord[NEDGE];
    __shared__ int   cnt[128];
    __shared__ int   off_[129];
    __shared__ int   fill[128];

    const int tid = threadIdx.x;
    const int g   = blockIdx.x;
    const float epl = 1.f + eps_all[l];
    const float* bt = bond_tabs + (size_t)l * FB * VV * EMB;

    if (tid < 128) { cnt[tid] = 0; fill[tid] = 0; }
    __syncthreads();
    if (tid < NEDGE) {
        const int s_ = edge_index[(g * 2 + 0) * NEDGE + tid];
        const int d_ = edge_index[(g * 2 + 1) * NEDGE + tid];
        es[tid] = s_ | (d_ << 8);
        const int base = (g * NEDGE + tid) * 3;
        eas[tid] = edge_attr[base + 0] | (edge_attr[base + 1] << 6) | (edge_attr[base + 2] << 12);
        atomicAdd(&cnt[d_], 1);
    }
    __syncthreads();
    if (tid < 64) {
        const int a = cnt[tid];
        const int b = cnt[64 + tid];
        int ia = a;
        #pragma unroll
        for (int o = 1; o < 64; o <<= 1) {
            int t = __shfl_up(ia, o, 64);
            if (tid >= o) ia += t;
        }
        const int totA = __shfl(ia, 63, 64);
        int ib = b;
        #pragma unroll
        for (int o = 1; o < 64; o <<= 1) {
            int t = __shfl_up(ib, o, 64);
            if (tid >= o) ib += t;
        }
        off_[tid]      = ia - a;
        off_[64 + tid] = totA + ib - b;
        if (tid == 63) off_[128] = totA + ib;
    }
    __syncthreads();
    if (tid < NEDGE) {
        const int d_ = es[tid] >> 8;
        const int pos = off_[d_] + atomicAdd(&fill[d_], 1);
        eord[pos] = tid;
    }

    const int wave = tid >> 6, lane = tid & 63;
    const int d0 = lane, d1 = lane + 64, d2 = lane + 128;

    for (int half = 0; half < 2; ++half) {
        const int doff = half * 150;
        __syncthreads();
        for (int idx = tid; idx < 128 * 150; idx += 1024) {
            const int i = idx / 150, d = idx - i * 150;
            hs[i * 152 + d] = h[(size_t)(g * 128 + i) * EMB + doff + d];
        }
        __syncthreads();
        for (int n = wave; n < 128; n += 16) {
            float acc0 = epl * hs[n * 152 + d0];
            float acc1 = (d1 < 150) ? epl * hs[n * 152 + d1] : 0.f;
            float acc2 = (d2 < 150) ? epl * hs[n * 152 + d2] : 0.f;
            const int eBeg = off_[n], eEnd = off_[n + 1];
            for (int ee = eBeg; ee < eEnd; ++ee) {
                const int e   = eord[ee];
                const int src = es[e] & 255;
                const int pk  = eas[e];
                const float* t0 = bt + ((pk) & 63) * EMB + doff;
                const float* t1 = bt + (64  + ((pk >> 6)  & 63)) * EMB + doff;
                const float* t2 = bt + (128 + ((pk >> 12) & 63)) * EMB + doff;
                acc0 += fmaxf(hs[src * 152 + d0] + t0[d0] + t1[d0] + t2[d0], 0.f);
                if (d1 < 150)
                    acc1 += fmaxf(hs[src * 152 + d1] + t0[d1] + t1[d1] + t2[d1], 0.f);
                if (d2 < 150)
                    acc2 += fmaxf(hs[src * 152 + d2] + t0[d2] + t1[d2] + t2[d2], 0.f);
            }
            float* hrow = h + (size_t)(g * 128 + n) * EMB + doff;
            hrow[d0] = acc0;
            if (d1 < 150) hrow[d1] = acc1;
            if (d2 < 150) hrow[d2] = acc2;
        }
    }
}

// ---------------------------------------------------------------------------
// Kernel 3: bf16 MFMA GEMM (unchanged)
// ---------------------------------------------------------------------------
template <int ABF16, int CBF16, int RELU>
__global__ __launch_bounds__(256)
void gemm_mfma(const void* __restrict__ Av, const int lda, const int Kreal,
               const int nT, const __bf16* __restrict__ B,
               void* __restrict__ Cv, const int ldc, const int Nreal,
               const float* __restrict__ bias, const float* __restrict__ gam,
               const float* __restrict__ bet)
{
    __shared__ unsigned short As[128 * 32];
    __shared__ unsigned short Bs[64 * 32];

    const int tid  = threadIdx.x;
    const int bn   = blockIdx.x * 64;
    const int bm   = blockIdx.y * 128;
    const int wid  = tid >> 6;
    const int lane = tid & 63;
    const int wm   = (wid >> 1) * 64;
    const int wn   = (wid & 1) * 32;
    const int lr   = lane & 15;
    const int kc   = (lane >> 4) * 8;
    const int KP   = nT * 32;

    f32x4 acc[4][2];
    #pragma unroll
    for (int mi = 0; mi < 4; ++mi)
        #pragma unroll
        for (int ni = 0; ni < 2; ++ni) acc[mi][ni] = (f32x4){0.f, 0.f, 0.f, 0.f};

    for (int t = 0; t < nT; ++t) {
        const int k0 = t * 32;
        {
            const int n = tid >> 2, k8 = (tid & 3) * 8;
            gload_lds16(B + (size_t)(bn + n) * KP + k0 + k8,
                        (char*)Bs + tid * 16);
        }
        if (ABF16) {
            const __bf16* A = (const __bf16*)Av;
            #pragma unroll
            for (int q = 0; q < 2; ++q) {
                const int idx = q * 256 + tid;
                const int m = idx >> 2, k8 = (idx & 3) * 8;
                gload_lds16(A + (size_t)(bm + m) * lda + k0 + k8,
                            (char*)As + idx * 16);
            }
        } else {
            const float* A = (const float*)Av;
            #pragma unroll
            for (int q = 0; q < 2; ++q) {
                const int idx = q * 256 + tid;
                const int m = idx >> 2;
                const int k = k0 + (idx & 3) * 8;
                const float* src = A + (size_t)(bm + m) * lda + k;
                float v[8];
                if (k + 7 < Kreal) {
                    const float4 u0 = *(const float4*)src;
                    const float4 u1 = *(const float4*)(src + 4);
                    v[0] = u0.x; v[1] = u0.y; v[2] = u0.z; v[3] = u0.w;
                    v[4] = u1.x; v[5] = u1.y; v[6] = u1.z; v[7] = u1.w;
                } else {
                    #pragma unroll
                    for (int j = 0; j < 8; ++j) v[j] = (k + j < Kreal) ? src[j] : 0.f;
                }
                bf16x8 p;
                #pragma unroll
                for (int j = 0; j < 8; ++j) p[j] = (__bf16)v[j];
                *(bf16x8*)&As[idx * 8] = p;
            }
        }
        __syncthreads();

        bf16x8 a[4], bfr[2];
        #pragma unroll
        for (int mi = 0; mi < 4; ++mi)
            a[mi] = *(const bf16x8*)&As[(wm + mi * 16 + lr) * 32 + kc];
        #pragma unroll
        for (int ni = 0; ni < 2; ++ni)
            bfr[ni] = *(const bf16x8*)&Bs[(wn + ni * 16 + lr) * 32 + kc];
        #pragma unroll
        for (int mi = 0; mi < 4; ++mi)
            #pragma unroll
            for (int ni = 0; ni < 2; ++ni)
                acc[mi][ni] = __builtin_amdgcn_mfma_f32_16x16x32_bf16(
                    a[mi], bfr[ni], acc[mi][ni], 0, 0, 0);
        __syncthreads();
    }

    #pragma unroll
    for (int ni = 0; ni < 2; ++ni) {
        const int n = bn + wn + ni * 16 + lr;
        const bool nv = (n < Nreal);
        const float gv = nv ? gam[n]  : 0.f;
        const float bv = nv ? bias[n] : 0.f;
        const float ev = nv ? bet[n]  : 0.f;
        #pragma unroll
        for (int mi = 0; mi < 4; ++mi) {
            #pragma unroll
            for (int r = 0; r < 4; ++r) {
                const size_t m = bm + wm + mi * 16 + (lane >> 4) * 4 + r;
                float v = gv * (acc[mi][ni][r] + bv) + ev;
                if (RELU) v = fmaxf(v, 0.f);
                if (CBF16) {
                    ((__bf16*)Cv)[m * ldc + n] = (__bf16)v;
                } else if (nv) {
                    ((float*)Cv)[m * ldc + n] = v;
                }
            }
        }
    }
}

// ---------------------------------------------------------------------------
extern "C" void kernel_launch(void* const* d_in, const int* in_sizes, int n_in,
                              void* d_out, int out_size, void* d_ws, size_t ws_size,
                              hipStream_t stream)
{
    const int*   order_p       = (const int*)d_in[0];
    const int*   x_atom        = (const int*)d_in[1];
    const int*   edge_index    = (const int*)d_in[2];
    const int*   edge_attr     = (const int*)d_in[3];
    const float* atom_tab      = (const float*)d_in[4];
    const float* bond_tab_root = (const float*)d_in[5];
    const float* edge_lin_w    = (const float*)d_in[6];
    const float* edge_lin_b    = (const float*)d_in[7];
    const float* bond_tabs     = (const float*)d_in[8];
    const float* eps           = (const float*)d_in[9];
    const float* w1            = (const float*)d_in[10];
    const float* b1            = (const float*)d_in[11];
    const float* bn1g          = (const float*)d_in[12];
    const float* bn1b          = (const float*)d_in[13];
    const float* w2            = (const float*)d_in[14];
    const float* b2            = (const float*)d_in[15];
    const float* bng           = (const float*)d_in[16];
    const float* bnb           = (const float*)d_in[17];

    float* h = (float*)d_out;   // [65536][300] fp32 master activations

    char* ws = (char*)d_ws;
    // A-split buffers live in z1's region (z1 only written after diffusion).
    __bf16* Ahi_g = (__bf16*)ws;                                // 17,825,792 B
    __bf16* Alo_g = (__bf16*)(ws + 17825792);                   // 17,825,792 B
    __bf16* z1    = (__bf16*)ws;                                // [65536][640]
    __bf16* w1t   = (__bf16*)(ws + 83886080);                   // [5][640][320]
    __bf16* w2t   = (__bf16*)(ws + 83886080 + 2048000);         // [5][320][640]

    prep_w_kernel<<<8000, 256, 0, stream>>>(w1, w2, w1t, w2t);

    adj_kernel<<<NGRAPH, 512, 0, stream>>>(edge_index, edge_attr, bond_tab_root,
                                           edge_lin_w, edge_lin_b, Ahi_g, Alo_g);

    diffuse_mm_kernel<<<NGRAPH, 512, 0, stream>>>(order_p, x_atom, atom_tab,
                                                  Ahi_g, Alo_g, h);

    for (int l = 0; l < NLAYER; ++l) {
        agg_kernel<<<NGRAPH, 1024, 0, stream>>>(edge_index, edge_attr, bond_tabs, eps, l, h);

        gemm_mfma<0, 1, 1><<<dim3(10, 512), 256, 0, stream>>>(
            h, EMB, 300, 10, w1t + (size_t)l * 640 * 320,
            z1, 640, 600, b1 + l * 600, bn1g + l * 600, bn1b + l * 600);

        if (l < NLAYER - 1) {
            gemm_mfma<1, 0, 1><<<dim3(5, 512), 256, 0, stream>>>(
                z1, 640, 640, 20, w2t + (size_t)l * 320 * 640,
                h, EMB, 300, b2 + l * 300, bng + l * 300, bnb + l * 300);
        } else {
            gemm_mfma<1, 0, 0><<<dim3(5, 512), 256, 0, stream>>>(
                z1, 640, 640, 20, w2t + (size_t)l * 320 * 640,
                h, EMB, 300, b2 + l * 300, bng + l * 300, bnb + l * 300);
        }
    }
}

// Round 6
// 1335.357 us; speedup vs baseline: 4.8177x; 1.4546x over previous
//
#include <hip/hip_runtime.h>

#define NGRAPH 512
#define NNODE  128
#define NEDGE  512
#define EMB    300
#define NLAYER 5
#define FA     9
#define FB     3
#define VV     64
#define KPAD   136   // padded K stride (bf16 elems) for A / xT tiles

typedef __bf16 bf16x8 __attribute__((ext_vector_type(8)));
typedef __bf16 bf16x4 __attribute__((ext_vector_type(4)));
typedef float  f32x4  __attribute__((ext_vector_type(4)));

__device__ __forceinline__ void gload_lds16(const void* gptr, void* lptr) {
    __builtin_amdgcn_global_load_lds(
        (const __attribute__((address_space(1))) void*)gptr,
        (__attribute__((address_space(3))) void*)lptr, 16, 0, 0);
}

// ---------------------------------------------------------------------------
// Kernel 0: weight prep — transpose w1/w2 to bf16 [N][K] (padded, zeros).
// ---------------------------------------------------------------------------
__global__ __launch_bounds__(256)
void prep_w_kernel(const float* __restrict__ w1, const float* __restrict__ w2,
                   __bf16* __restrict__ w1t, __bf16* __restrict__ w2t)
{
    const int i = blockIdx.x * 256 + threadIdx.x;
    const int T1 = NLAYER * 640 * 320;
    const int T2 = NLAYER * 320 * 640;
    if (i < T1) {
        const int l = i / (640 * 320);
        const int r = i - l * 640 * 320;
        const int n = r / 320, k = r - n * 320;
        float v = (n < 600 && k < 300) ? w1[((size_t)l * 300 + k) * 600 + n] : 0.f;
        w1t[i] = (__bf16)v;
    } else if (i < T1 + T2) {
        const int j = i - T1;
        const int l = j / (320 * 640);
        const int r = j - l * 320 * 640;
        const int n = r / 640, k = r - n * 640;
        float v = (n < 300 && k < 600) ? w2[((size_t)l * 600 + k) * 300 + n] : 0.f;
        w2t[j] = (__bf16)v;
    }
}

// ---------------------------------------------------------------------------
// Kernel 1a: adjacency build (unchanged from round 5)
// ---------------------------------------------------------------------------
__global__ __launch_bounds__(512)
void adj_kernel(const int* __restrict__ edge_index,
                const int* __restrict__ edge_attr,
                const float* __restrict__ bond_tab_root,
                const float* __restrict__ edge_lin_w,
                const float* __restrict__ edge_lin_b,
                __bf16* __restrict__ Ahi_g, __bf16* __restrict__ Alo_g)
{
    __shared__ float A[128 * 129];     // int view during prio phase
    __shared__ float ew_s[NEDGE];
    __shared__ int   es[NEDGE];
    __shared__ float rinv[128];
    __shared__ float cinv[128];

    const int tid = threadIdx.x;
    const int g   = blockIdx.x;
    int* Ai = (int*)A;

    for (int e = tid; e < NEDGE; e += 512) {
        int r = edge_index[(g * 2 + 0) * NEDGE + e];
        int c = edge_index[(g * 2 + 1) * NEDGE + e];
        es[e] = r | (c << 8);
    }
    for (int i = tid; i < 128 * 129; i += 512) Ai[i] = -1;
    __syncthreads();

    {
        const int wave = tid >> 6, lane = tid & 63;
        const float elb = edge_lin_b[0];
        for (int e = wave * 64; e < wave * 64 + 64; ++e) {
            const int base = (g * NEDGE + e) * 3;
            const int a0 = edge_attr[base + 0];
            const int a1 = edge_attr[base + 1];
            const int a2 = edge_attr[base + 2];
            const float* t0 = bond_tab_root + (0 * VV + a0) * EMB;
            const float* t1 = bond_tab_root + (1 * VV + a1) * EMB;
            const float* t2 = bond_tab_root + (2 * VV + a2) * EMB;
            float acc = 0.f;
            for (int d = lane; d < EMB; d += 64)
                acc += (t0[d] + t1[d] + t2[d]) * edge_lin_w[d];
            #pragma unroll
            for (int off = 32; off > 0; off >>= 1) acc += __shfl_xor(acc, off, 64);
            if (lane == 0) ew_s[e] = 1.f / (1.f + expf(-(acc + elb)));
        }
    }
    for (int e = tid; e < NEDGE; e += 512) {
        int r = es[e] & 255, c = es[e] >> 8;
        atomicMax(&Ai[r * 129 + c], e);
        atomicMax(&Ai[c * 129 + r], 512 + e);
    }
    __syncthreads();
    for (int i = tid; i < 128 * 129; i += 512) {
        int p = Ai[i];
        A[i] = (p < 0) ? 0.f : ew_s[p & 511];
    }
    __syncthreads();
    if (tid < 128) A[tid * 129 + tid] += 1.f;
    __syncthreads();
    if (tid < 128) {
        float rs = 0.f, cs = 0.f;
        for (int j = 0; j < 128; ++j) { rs += A[tid * 129 + j]; cs += A[j * 129 + tid]; }
        rinv[tid] = 1.f / sqrtf(rs);
        cinv[tid] = 1.f / sqrtf(cs);
    }
    __syncthreads();
    for (int i = tid; i < 128 * KPAD; i += 512) {
        const int m = i / KPAD, k = i - m * KPAD;
        float v = (k < 128) ? A[m * 129 + k] * cinv[m] * rinv[k] : 0.f;
        __bf16 hi = (__bf16)v;
        Ahi_g[(size_t)g * 128 * KPAD + i] = hi;
        Alo_g[(size_t)g * 128 * KPAD + i] = (__bf16)(v - (float)hi);
    }
}

// ---------------------------------------------------------------------------
// Kernel 1b: diffusion via MFMA with split-bf16 (unchanged from round 5)
// ---------------------------------------------------------------------------
__global__ __launch_bounds__(512)
void diffuse_mm_kernel(const int* __restrict__ order_p,
                       const int* __restrict__ x_atom,
                       const float* __restrict__ atom_tab,
                       const __bf16* __restrict__ Ahi_g,
                       const __bf16* __restrict__ Alo_g,
                       float* __restrict__ h)
{
    __shared__ __bf16 Ahi[128 * KPAD];
    __shared__ __bf16 Alo[128 * KPAD];
    __shared__ __bf16 xt[4 * 64 * KPAD];
    __shared__ int    xat[128 * FA];

    const int tid  = threadIdx.x;
    const int g    = blockIdx.x;
    const int lane = tid & 63;
    const int wid  = tid >> 6;
    const int wm   = (wid >> 1) * 32;
    const int wn   = (wid & 1) * 32;
    const int lr   = lane & 15;
    const int q4   = (lane >> 4) * 4;
    const int kc   = (lane >> 4) * 8;

    for (int idx = tid; idx < 128 * KPAD / 8; idx += 512) {
        gload_lds16(Ahi_g + (size_t)g * 128 * KPAD + idx * 8, (char*)Ahi + idx * 16);
        gload_lds16(Alo_g + (size_t)g * 128 * KPAD + idx * 8, (char*)Alo + idx * 16);
    }
    for (int i = tid; i < 128 * FA; i += 512) xat[i] = x_atom[g * 128 * FA + i];
    __syncthreads();   // xat visible to ALL waves before encode reads it

    const int   ord    = order_p[0];
    const float yscale = 1.f / (float)(ord + 1);

    for (int cb = 0; cb < 5; ++cb) {
        const int dbase = cb * 64;

        float yacc[2][2][4];
        #pragma unroll
        for (int mi = 0; mi < 2; ++mi) {
            #pragma unroll
            for (int ni = 0; ni < 2; ++ni) {
                const int n_ = wn + ni * 16 + lr;
                const int d  = dbase + n_;
                #pragma unroll
                for (int r = 0; r < 4; ++r) {
                    const int m_ = wm + mi * 16 + q4 + r;
                    float v = 0.f;
                    if (d < EMB) {
                        #pragma unroll
                        for (int f = 0; f < FA; ++f)
                            v += atom_tab[(size_t)((f << 6) + xat[m_ * FA + f]) * EMB + d];
                        v *= 0.8f;
                    }
                    yacc[mi][ni][r] = v;
                    __bf16 hi = (__bf16)v;
                    xt[0 * 64 * KPAD + n_ * KPAD + m_] = hi;
                    xt[1 * 64 * KPAD + n_ * KPAD + m_] = (__bf16)(v - (float)hi);
                }
            }
        }
        __syncthreads();

        int curbuf = 0;
        for (int o = 0; o < ord; ++o) {
            const __bf16* xh = xt + (curbuf * 2 + 0) * 64 * KPAD;
            const __bf16* xl = xt + (curbuf * 2 + 1) * 64 * KPAD;
            f32x4 racc[2][2];
            #pragma unroll
            for (int mi = 0; mi < 2; ++mi)
                #pragma unroll
                for (int ni = 0; ni < 2; ++ni) racc[mi][ni] = (f32x4){0.f, 0.f, 0.f, 0.f};

            #pragma unroll
            for (int ks = 0; ks < 4; ++ks) {
                const int k0 = ks * 32 + kc;
                bf16x8 ah[2], al[2], bh[2], bl[2];
                #pragma unroll
                for (int mi = 0; mi < 2; ++mi) {
                    ah[mi] = *(const bf16x8*)&Ahi[(wm + mi * 16 + lr) * KPAD + k0];
                    al[mi] = *(const bf16x8*)&Alo[(wm + mi * 16 + lr) * KPAD + k0];
                }
                #pragma unroll
                for (int ni = 0; ni < 2; ++ni) {
                    bh[ni] = *(const bf16x8*)&xh[(wn + ni * 16 + lr) * KPAD + k0];
                    bl[ni] = *(const bf16x8*)&xl[(wn + ni * 16 + lr) * KPAD + k0];
                }
                #pragma unroll
                for (int mi = 0; mi < 2; ++mi) {
                    #pragma unroll
                    for (int ni = 0; ni < 2; ++ni) {
                        racc[mi][ni] = __builtin_amdgcn_mfma_f32_16x16x32_bf16(
                            ah[mi], bh[ni], racc[mi][ni], 0, 0, 0);
                        racc[mi][ni] = __builtin_amdgcn_mfma_f32_16x16x32_bf16(
                            ah[mi], bl[ni], racc[mi][ni], 0, 0, 0);
                        racc[mi][ni] = __builtin_amdgcn_mfma_f32_16x16x32_bf16(
                            al[mi], bh[ni], racc[mi][ni], 0, 0, 0);
                    }
                }
            }

            __bf16* nh = xt + ((curbuf ^ 1) * 2 + 0) * 64 * KPAD;
            __bf16* nl = xt + ((curbuf ^ 1) * 2 + 1) * 64 * KPAD;
            #pragma unroll
            for (int mi = 0; mi < 2; ++mi) {
                #pragma unroll
                for (int ni = 0; ni < 2; ++ni) {
                    const int n_ = wn + ni * 16 + lr;
                    const int mbase = wm + mi * 16 + q4;
                    bf16x4 hv, lv;
                    #pragma unroll
                    for (int r = 0; r < 4; ++r) {
                        const float v = racc[mi][ni][r];
                        yacc[mi][ni][r] += v;
                        __bf16 hi = (__bf16)v;
                        hv[r] = hi;
                        lv[r] = (__bf16)(v - (float)hi);
                    }
                    *(bf16x4*)&nh[n_ * KPAD + mbase] = hv;
                    *(bf16x4*)&nl[n_ * KPAD + mbase] = lv;
                }
            }
            __syncthreads();
            curbuf ^= 1;
        }

        #pragma unroll
        for (int mi = 0; mi < 2; ++mi) {
            #pragma unroll
            for (int ni = 0; ni < 2; ++ni) {
                const int n_ = wn + ni * 16 + lr;
                const int d  = dbase + n_;
                if (d < EMB) {
                    #pragma unroll
                    for (int r = 0; r < 4; ++r) {
                        const int m_ = wm + mi * 16 + q4 + r;
                        h[(size_t)(g * 128 + m_) * EMB + d] = yacc[mi][ni][r] * yscale;
                    }
                }
            }
        }
    }
}

// ---------------------------------------------------------------------------
// Kernel 2: GIN aggregation, CSR gather version (unchanged).
// ---------------------------------------------------------------------------
__global__ __launch_bounds__(1024)
void agg_kernel(const int* __restrict__ edge_index,
                const int* __restrict__ edge_attr,
                const float* __restrict__ bond_tabs,
                const float* __restrict__ eps_all,
                const int l,
                float* __restrict__ h)
{
    __shared__ float hs[128 * 152];
    __shared__ int   es[NEDGE];
    __shared__ int   eas[NEDGE];
    __shared__ int   eord[NEDGE];
    __shared__ int   cnt[128];
    __shared__ int   off_[129];
    __shared__ int   fill[128];

    const int tid = threadIdx.x;
    const int g   = blockIdx.x;
    const float epl = 1.f + eps_all[l];
    const float* bt = bond_tabs + (size_t)l * FB * VV * EMB;

    if (tid < 128) { cnt[tid] = 0; fill[tid] = 0; }
    __syncthreads();
    if (tid < NEDGE) {
        const int s_ = edge_index[(g * 2 + 0) * NEDGE + tid];
        const int d_ = edge_index[(g * 2 + 1) * NEDGE + tid];
        es[tid] = s_ | (d_ << 8);
        const int base = (g * NEDGE + tid) * 3;
        eas[tid] = edge_attr[base + 0] | (edge_attr[base + 1] << 6) | (edge_attr[base + 2] << 12);
        atomicAdd(&cnt[d_], 1);
    }
    __syncthreads();
    if (tid < 64) {
        const int a = cnt[tid];
        const int b = cnt[64 + tid];
        int ia = a;
        #pragma unroll
        for (int o = 1; o < 64; o <<= 1) {
            int t = __shfl_up(ia, o, 64);
            if (tid >= o) ia += t;
        }
        const int totA = __shfl(ia, 63, 64);
        int ib = b;
        #pragma unroll
        for (int o = 1; o < 64; o <<= 1) {
            int t = __shfl_up(ib, o, 64);
            if (tid >= o) ib += t;
        }
        off_[tid]      = ia - a;
        off_[64 + tid] = totA + ib - b;
        if (tid == 63) off_[128] = totA + ib;
    }
    __syncthreads();
    if (tid < NEDGE) {
        const int d_ = es[tid] >> 8;
        const int pos = off_[d_] + atomicAdd(&fill[d_], 1);
        eord[pos] = tid;
    }

    const int wave = tid >> 6, lane = tid & 63;
    const int d0 = lane, d1 = lane + 64, d2 = lane + 128;

    for (int half = 0; half < 2; ++half) {
        const int doff = half * 150;
        __syncthreads();
        for (int idx = tid; idx < 128 * 150; idx += 1024) {
            const int i = idx / 150, d = idx - i * 150;
            hs[i * 152 + d] = h[(size_t)(g * 128 + i) * EMB + doff + d];
        }
        __syncthreads();
        for (int n = wave; n < 128; n += 16) {
            float acc0 = epl * hs[n * 152 + d0];
            float acc1 = (d1 < 150) ? epl * hs[n * 152 + d1] : 0.f;
            float acc2 = (d2 < 150) ? epl * hs[n * 152 + d2] : 0.f;
            const int eBeg = off_[n], eEnd = off_[n + 1];
            for (int ee = eBeg; ee < eEnd; ++ee) {
                const int e   = eord[ee];
                const int src = es[e] & 255;
                const int pk  = eas[e];
                const float* t0 = bt + ((pk) & 63) * EMB + doff;
                const float* t1 = bt + (64  + ((pk >> 6)  & 63)) * EMB + doff;
                const float* t2 = bt + (128 + ((pk >> 12) & 63)) * EMB + doff;
                acc0 += fmaxf(hs[src * 152 + d0] + t0[d0] + t1[d0] + t2[d0], 0.f);
                if (d1 < 150)
                    acc1 += fmaxf(hs[src * 152 + d1] + t0[d1] + t1[d1] + t2[d1], 0.f);
                if (d2 < 150)
                    acc2 += fmaxf(hs[src * 152 + d2] + t0[d2] + t1[d2] + t2[d2], 0.f);
            }
            float* hrow = h + (size_t)(g * 128 + n) * EMB + doff;
            hrow[d0] = acc0;
            if (d1 < 150) hrow[d1] = acc1;
            if (d2 < 150) hrow[d2] = acc2;
        }
    }
}

// ---------------------------------------------------------------------------
// Kernel 3: bf16 MFMA GEMM with XCD-chunk swizzle.
// 1D grid; logical block id lg = (hw%8)*(nwg/8) + hw/8 so all N-blocks
// sharing an A row-tile land on ONE XCD -> A re-reads hit that XCD's L2.
// nwg MUST be divisible by 8 (5120 / 2560: ok).
// ---------------------------------------------------------------------------
template <int ABF16, int CBF16, int RELU>
__global__ __launch_bounds__(256)
void gemm_mfma(const void* __restrict__ Av, const int lda, const int Kreal,
               const int nT, const int nBlkN, const __bf16* __restrict__ B,
               void* __restrict__ Cv, const int ldc, const int Nreal,
               const float* __restrict__ bias, const float* __restrict__ gam,
               const float* __restrict__ bet)
{
    __shared__ unsigned short As[128 * 32];
    __shared__ unsigned short Bs[64 * 32];

    const int tid  = threadIdx.x;
    const int nwg  = gridDim.x;
    const int hw   = blockIdx.x;
    const int lg   = (hw & 7) * (nwg >> 3) + (hw >> 3);   // XCD-chunk swizzle
    const int bn   = (lg % nBlkN) * 64;
    const int bm   = (lg / nBlkN) * 128;
    const int wid  = tid >> 6;
    const int lane = tid & 63;
    const int wm   = (wid >> 1) * 64;
    const int wn   = (wid & 1) * 32;
    const int lr   = lane & 15;
    const int kc   = (lane >> 4) * 8;
    const int KP   = nT * 32;

    f32x4 acc[4][2];
    #pragma unroll
    for (int mi = 0; mi < 4; ++mi)
        #pragma unroll
        for (int ni = 0; ni < 2; ++ni) acc[mi][ni] = (f32x4){0.f, 0.f, 0.f, 0.f};

    for (int t = 0; t < nT; ++t) {
        const int k0 = t * 32;
        {
            const int n = tid >> 2, k8 = (tid & 3) * 8;
            gload_lds16(B + (size_t)(bn + n) * KP + k0 + k8,
                        (char*)Bs + tid * 16);
        }
        if (ABF16) {
            const __bf16* A = (const __bf16*)Av;
            #pragma unroll
            for (int q = 0; q < 2; ++q) {
                const int idx = q * 256 + tid;
                const int m = idx >> 2, k8 = (idx & 3) * 8;
                gload_lds16(A + (size_t)(bm + m) * lda + k0 + k8,
                            (char*)As + idx * 16);
            }
        } else {
            const float* A = (const float*)Av;
            #pragma unroll
            for (int q = 0; q < 2; ++q) {
                const int idx = q * 256 + tid;
                const int m = idx >> 2;
                const int k = k0 + (idx & 3) * 8;
                const float* src = A + (size_t)(bm + m) * lda + k;
                float v[8];
                if (k + 7 < Kreal) {
                    const float4 u0 = *(const float4*)src;
                    const float4 u1 = *(const float4*)(src + 4);
                    v[0] = u0.x; v[1] = u0.y; v[2] = u0.z; v[3] = u0.w;
                    v[4] = u1.x; v[5] = u1.y; v[6] = u1.z; v[7] = u1.w;
                } else {
                    #pragma unroll
                    for (int j = 0; j < 8; ++j) v[j] = (k + j < Kreal) ? src[j] : 0.f;
                }
                bf16x8 p;
                #pragma unroll
                for (int j = 0; j < 8; ++j) p[j] = (__bf16)v[j];
                *(bf16x8*)&As[idx * 8] = p;
            }
        }
        __syncthreads();

        bf16x8 a[4], bfr[2];
        #pragma unroll
        for (int mi = 0; mi < 4; ++mi)
            a[mi] = *(const bf16x8*)&As[(wm + mi * 16 + lr) * 32 + kc];
        #pragma unroll
        for (int ni = 0; ni < 2; ++ni)
            bfr[ni] = *(const bf16x8*)&Bs[(wn + ni * 16 + lr) * 32 + kc];
        #pragma unroll
        for (int mi = 0; mi < 4; ++mi)
            #pragma unroll
            for (int ni = 0; ni < 2; ++ni)
                acc[mi][ni] = __builtin_amdgcn_mfma_f32_16x16x32_bf16(
                    a[mi], bfr[ni], acc[mi][ni], 0, 0, 0);
        __syncthreads();
    }

    #pragma unroll
    for (int ni = 0; ni < 2; ++ni) {
        const int n = bn + wn + ni * 16 + lr;
        const bool nv = (n < Nreal);
        const float gv = nv ? gam[n]  : 0.f;
        const float bv = nv ? bias[n] : 0.f;
        const float ev = nv ? bet[n]  : 0.f;
        #pragma unroll
        for (int mi = 0; mi < 4; ++mi) {
            #pragma unroll
            for (int r = 0; r < 4; ++r) {
                const size_t m = bm + wm + mi * 16 + (lane >> 4) * 4 + r;
                float v = gv * (acc[mi][ni][r] + bv) + ev;
                if (RELU) v = fmaxf(v, 0.f);
                if (CBF16) {
                    ((__bf16*)Cv)[m * ldc + n] = (__bf16)v;
                } else if (nv) {
                    ((float*)Cv)[m * ldc + n] = v;
                }
            }
        }
    }
}

// ---------------------------------------------------------------------------
extern "C" void kernel_launch(void* const* d_in, const int* in_sizes, int n_in,
                              void* d_out, int out_size, void* d_ws, size_t ws_size,
                              hipStream_t stream)
{
    const int*   order_p       = (const int*)d_in[0];
    const int*   x_atom        = (const int*)d_in[1];
    const int*   edge_index    = (const int*)d_in[2];
    const int*   edge_attr     = (const int*)d_in[3];
    const float* atom_tab      = (const float*)d_in[4];
    const float* bond_tab_root = (const float*)d_in[5];
    const float* edge_lin_w    = (const float*)d_in[6];
    const float* edge_lin_b    = (const float*)d_in[7];
    const float* bond_tabs     = (const float*)d_in[8];
    const float* eps           = (const float*)d_in[9];
    const float* w1            = (const float*)d_in[10];
    const float* b1            = (const float*)d_in[11];
    const float* bn1g          = (const float*)d_in[12];
    const float* bn1b          = (const float*)d_in[13];
    const float* w2            = (const float*)d_in[14];
    const float* b2            = (const float*)d_in[15];
    const float* bng           = (const float*)d_in[16];
    const float* bnb           = (const float*)d_in[17];

    float* h = (float*)d_out;   // [65536][300] fp32 master activations

    char* ws = (char*)d_ws;
    // A-split buffers live in z1's region (z1 only written after diffusion).
    __bf16* Ahi_g = (__bf16*)ws;                                // 17,825,792 B
    __bf16* Alo_g = (__bf16*)(ws + 17825792);                   // 17,825,792 B
    __bf16* z1    = (__bf16*)ws;                                // [65536][640]
    __bf16* w1t   = (__bf16*)(ws + 83886080);                   // [5][640][320]
    __bf16* w2t   = (__bf16*)(ws + 83886080 + 2048000);         // [5][320][640]

    prep_w_kernel<<<8000, 256, 0, stream>>>(w1, w2, w1t, w2t);

    adj_kernel<<<NGRAPH, 512, 0, stream>>>(edge_index, edge_attr, bond_tab_root,
                                           edge_lin_w, edge_lin_b, Ahi_g, Alo_g);

    diffuse_mm_kernel<<<NGRAPH, 512, 0, stream>>>(order_p, x_atom, atom_tab,
                                                  Ahi_g, Alo_g, h);

    for (int l = 0; l < NLAYER; ++l) {
        agg_kernel<<<NGRAPH, 1024, 0, stream>>>(edge_index, edge_attr, bond_tabs, eps, l, h);

        // gemm1: 5120 blocks (10 N-tiles x 512 M-tiles), XCD-swizzled inside
        gemm_mfma<0, 1, 1><<<5120, 256, 0, stream>>>(
            h, EMB, 300, 10, 10, w1t + (size_t)l * 640 * 320,
            z1, 640, 600, b1 + l * 600, bn1g + l * 600, bn1b + l * 600);

        // gemm2: 2560 blocks (5 N-tiles x 512 M-tiles)
        if (l < NLAYER - 1) {
            gemm_mfma<1, 0, 1><<<2560, 256, 0, stream>>>(
                z1, 640, 640, 20, 5, w2t + (size_t)l * 320 * 640,
                h, EMB, 300, b2 + l * 300, bng + l * 300, bnb + l * 300);
        } else {
            gemm_mfma<1, 0, 0><<<2560, 256, 0, stream>>>(
                z1, 640, 640, 20, 5, w2t + (size_t)l * 320 * 640,
                h, EMB, 300, b2 + l * 300, bng + l * 300, bnb + l * 300);
        }
    }
}